// Round 9
// baseline (2074.832 us; speedup 1.0000x reference)
//
#include <hip/hip_runtime.h>
#include <cstdint>
#include <cstddef>

#define DEVINL __device__ __forceinline__

typedef __attribute__((ext_vector_type(8))) short bf16x8;
typedef __attribute__((ext_vector_type(4))) float f32x4;
typedef __attribute__((ext_vector_type(4))) unsigned short u16x4;
typedef __attribute__((ext_vector_type(4))) unsigned int u32x4;

// ---------- workspace layout ----------
static constexpr size_t OFF_XB   = 0;                              // x bf16 [32768][1024]
static constexpr size_t OFF_WHT  = OFF_XB  + (size_t)32768*1024*2; // Wh^T bf16 [4096][1024]
static constexpr size_t OFF_WXT  = OFF_WHT + (size_t)4096*1024*2;  // Wx^T bf16 [4096][1024]
static constexpr size_t OFF_WCT  = OFF_WXT + (size_t)4096*1024*2;  // Wc^T bf16 [1024][1024]
static constexpr size_t OFF_BIAS = OFF_WCT + (size_t)1024*1024*2;  // bias_all f32 [4096]
static constexpr size_t OFF_XW   = OFF_BIAS + 4096*4;              // XW bf16 [32768][4096]
static constexpr size_t OFF_H    = OFF_XW  + (size_t)32768*4096*2; // h bf16 [32768][1024]
static constexpr size_t OFF_CB   = OFF_H   + (size_t)32768*1024*2; // cell bf16 x2 [128][1024]
static constexpr size_t OFF_BAR  = OFF_CB  + (size_t)2*128*1024*2; // flag lines, 16 KB
static constexpr size_t WS_NEEDED = OFF_BAR + 16384;

// ---------- helpers ----------
DEVINL unsigned short f2b(float f) {
  union { float f; unsigned u; } v; v.f = f;
  unsigned r = (v.u + 0x7FFFu + ((v.u >> 16) & 1u)) >> 16;  // RNE
  return (unsigned short)r;
}
DEVINL float b2f(unsigned short h) {
  union { unsigned u; float f; } v; v.u = ((unsigned)h) << 16;
  return v.f;
}
DEVINL float sigmoidf_(float x) { return 1.0f / (1.0f + __expf(-x)); }
DEVINL float tanhf_(float x) { float e = __expf(2.0f * x); return 1.0f - 2.0f / (e + 1.0f); }
DEVINL f32x4 MFMA(bf16x8 a, bf16x8 b, f32x4 c) {
  return __builtin_amdgcn_mfma_f32_16x16x32_bf16(a, b, c, 0, 0, 0);
}
DEVINL void gload16(const void* g, void* l) {
  __builtin_amdgcn_global_load_lds(
      (const __attribute__((address_space(1))) void*)g,
      (__attribute__((address_space(3))) void*)l, 16, 0, 0);
}

// ---------- conversions ----------
__global__ void cvt_x_kernel(const float* __restrict__ x, unsigned short* __restrict__ xb) {
  size_t i = ((size_t)blockIdx.x * 256 + threadIdx.x) * 4;
  float4 v = *(const float4*)(x + i);
  u16x4 o; o.x = f2b(v.x); o.y = f2b(v.y); o.z = f2b(v.z); o.w = f2b(v.w);
  *(u16x4*)(xb + i) = o;
}

// coalesced transpose-convert via 64x64 LDS tile:
// WhT[4j+g][k] = Wg[k][j];  WxT[4j+g][k] = Wg[1024+k][j]
__global__ __launch_bounds__(256)
void cvt_w_kernel(const float* __restrict__ Wf, const float* __restrict__ Wi1,
                  const float* __restrict__ Wi2, const float* __restrict__ Wo,
                  unsigned short* __restrict__ WhT, unsigned short* __restrict__ WxT) {
  __shared__ float tile[64][65];
  const int bid = blockIdx.x;          // 16 jt x 16 kt x 4 g = 1024 blocks
  const int g  = bid & 3;
  const int kt = (bid >> 2) & 15;
  const int jt = bid >> 6;
  const float* W = (g == 0) ? Wf : (g == 1) ? Wi1 : (g == 2) ? Wi2 : Wo;
  const int tid = threadIdx.x;
  const int jj  = tid & 63;
  const int kr  = tid >> 6;            // 0..3

  for (int h = 0; h < 2; ++h) {
    const float* Wb = W + (size_t)(h ? 1024 : 0) * 1024;
#pragma unroll
    for (int i = 0; i < 16; ++i) {     // coalesced f32 reads: 64 consecutive j
      int kl = i * 4 + kr;
      tile[kl][jj] = Wb[(size_t)(kt * 64 + kl) * 1024 + jt * 64 + jj];
    }
    __syncthreads();
    unsigned short* Out = h ? WxT : WhT;
    unsigned short* op  = Out + (size_t)(4 * (jt * 64 + jj) + g) * 1024 + kt * 64 + kr * 16;
#pragma unroll
    for (int q = 0; q < 4; ++q) {
      u16x4 v;
#pragma unroll
      for (int e = 0; e < 4; ++e)
        ((unsigned short*)&v)[e] = f2b(tile[kr * 16 + q * 4 + e][jj]);
      *(u16x4*)(op + q * 4) = v;
    }
    __syncthreads();                   // before tile reuse
  }
}

__global__ void bias_kernel(const float* __restrict__ bf_, const float* __restrict__ bi1,
                            const float* __restrict__ bi2, const float* __restrict__ bo,
                            float* __restrict__ biasAll) {
  int gc = blockIdx.x * 256 + threadIdx.x;   // 4096
  int j = gc >> 2, g = gc & 3;
  const float* bb = (g == 0) ? bf_ : (g == 1) ? bi1 : (g == 2) ? bi2 : bo;
  biasAll[gc] = bb[j];
}

__global__ void cvt_wc_kernel(const float* __restrict__ Wc, unsigned short* __restrict__ WcT) {
  int idx = blockIdx.x * 256 + threadIdx.x;   // 1024*1024 total
  int k = idx & 1023, n = idx >> 10;
  WcT[idx] = f2b(Wc[(size_t)k * 1024 + n]);
}

// ---------- 128x128 bf16 GEMM, B given as B^T [N][K], C = A@B + bias ----------
template<bool OUT_F32>
__global__ __launch_bounds__(256)
void gemm_bt(const unsigned short* __restrict__ A,   // [M][K] bf16
             const unsigned short* __restrict__ Bt,  // [N][K] bf16
             const float* __restrict__ bias,         // [N] f32
             void* __restrict__ C,
             int M, int N, int K) {
  __shared__ unsigned short sA[128 * 64];
  __shared__ unsigned short sB[128 * 64];
  const int tid  = threadIdx.x;
  const int lane = tid & 63;
  const int wid  = tid >> 6;

  // bijective XCD swizzle (grids are %8==0)
  const int nwg = gridDim.x * gridDim.y;
  const int lin = blockIdx.y * gridDim.x + blockIdx.x;
  const int cpx = nwg >> 3;
  const int swz = (lin & 7) * cpx + (lin >> 3);
  const int m0  = (swz / gridDim.x) * 128;
  const int n0  = (swz % gridDim.x) * 128;

  const int wm = (wid >> 1) * 64;
  const int wn = (wid & 1) * 64;

  f32x4 acc[4][4];
#pragma unroll
  for (int i = 0; i < 4; ++i)
#pragma unroll
    for (int j = 0; j < 4; ++j) acc[i][j] = (f32x4){0.f, 0.f, 0.f, 0.f};

  for (int k0 = 0; k0 < K; k0 += 64) {
#pragma unroll
    for (int p = 0; p < 4; ++p) {
      int t = p * 256 + tid;
      int r = t >> 3, c = t & 7;
      gload16(A  + (size_t)(m0 + r) * K + k0 + c * 8, (char*)sA + p * 4096 + wid * 1024);
      gload16(Bt + (size_t)(n0 + r) * K + k0 + c * 8, (char*)sB + p * 4096 + wid * 1024);
    }
    __syncthreads();
#pragma unroll
    for (int kk = 0; kk < 2; ++kk) {
      bf16x8 av[4], bv[4];
#pragma unroll
      for (int mi = 0; mi < 4; ++mi)
        av[mi] = *(const bf16x8*)&sA[(wm + mi * 16 + (lane & 15)) * 64 + kk * 32 + (lane >> 4) * 8];
#pragma unroll
      for (int ni = 0; ni < 4; ++ni)
        bv[ni] = *(const bf16x8*)&sB[(wn + ni * 16 + (lane & 15)) * 64 + kk * 32 + (lane >> 4) * 8];
#pragma unroll
      for (int mi = 0; mi < 4; ++mi)
#pragma unroll
        for (int ni = 0; ni < 4; ++ni)
          acc[mi][ni] = MFMA(av[mi], bv[ni], acc[mi][ni]);
    }
    __syncthreads();
  }

#pragma unroll
  for (int mi = 0; mi < 4; ++mi)
#pragma unroll
    for (int ni = 0; ni < 4; ++ni)
#pragma unroll
      for (int r = 0; r < 4; ++r) {
        int row = m0 + wm + mi * 16 + (lane >> 4) * 4 + r;
        int col = n0 + wn + ni * 16 + (lane & 15);
        float v = acc[mi][ni][r] + bias[col];
        if (OUT_F32) ((float*)C)[(size_t)row * N + col] = v;
        else ((unsigned short*)C)[(size_t)row * N + col] = f2b(v);
      }
}

// ---------- persistent recurrence v9: RMW-free flag barrier, 128 WGs ----------
// 128 WGs x 512 threads (cooperative). WG (mq, cs2): mq = wgid&3 -> rows
// 32*mq..+32 (4 independent quarters); cs2 = wgid>>2 (0..31) -> gate-cols
// 128*cs2..+128 (= cell cols 32*cs2..+32). Wave nh (0..7): gate-cols
// 128cs2+16nh..+16, BOTH 16-row m-tiles (2 independent acc chains, 64 MFMA).
// MALL data protocol identical to proven v5/v7/v8: cell stores = relaxed
// agent atomics; cell loads = sc0|sc1 asm loads; H plain cached.
// NEW barrier: RMW-free. Per quarter, 32 flag words (one per WG). Leader
// stores epoch t+1 to ITS OWN flag after the vmcnt-draining __syncthreads;
// at top of step t every wave spins until all 32 flags >= t (lane L watches
// flag L&31). No atomic contention, no fences, 3 RTTs total.
__global__ __launch_bounds__(512, 2)
void lstm_persist(const unsigned short* __restrict__ WhT,  // [4096][1024] bf16
                  const unsigned short* __restrict__ XW,   // [32768][4096] bf16
                  unsigned short* __restrict__ H,          // [32768][1024] bf16
                  unsigned short* __restrict__ cB0,        // [128][1024] bf16
                  unsigned short* __restrict__ cB1,
                  float* __restrict__ cellOut,             // [128][1024] f32
                  unsigned* __restrict__ bar) {
  __shared__ __align__(16) char  sA[32 * 2048];   // 64 KB A-tile, swizzled layout
  __shared__ __align__(16) float sP[32 * 132];    // 16.9 KB preact redistribute

  const int tid  = threadIdx.x;
  const int lane = tid & 63;
  const int nh   = tid >> 6;       // wave id = n-tile 0..7
  const int wgid = blockIdx.x;
  const int mq   = wgid & 3;       // row quarter
  const int cs2  = wgid >> 2;      // col slice 0..31 (128 gate-cols each)

  unsigned* fl = bar + mq * 64;    // 32 flags (own 256B region per quarter)

  const int r0 = lane & 15;        // col within n-tile / row within m-tile
  const int ch = lane >> 4;        // 16B chunk id within K-slice
  const int r7 = r0 & 7;

  // ---- Wh fragments: 32 x bf16x8 per lane (128 regs), volatile loads ----
  bf16x8 bfr[32];
  {
    const unsigned short* bp = WhT + (size_t)(cs2 * 128 + nh * 16 + r0) * 1024 + ch * 8;
#pragma unroll
    for (int ks = 0; ks < 32; ++ks)
      bfr[ks] = *(const volatile bf16x8*)(bp + ks * 32);
  }

  // ---- per-thread cell ownership: 2 consecutive cell cols ----
  const int b_local = tid >> 4;          // 0..31
  const int jp      = (tid & 15) * 2;    // 0,2,..,30
  const int browg   = mq * 32 + b_local; // global batch row
  float cf0 = 0.f, cf1 = 0.f;

  const unsigned short* xwp = XW + (size_t)browg * 256 * 4096 + cs2 * 128 + jp * 4;
  unsigned* c0p = (unsigned*)(cB0 + (size_t)browg * 1024 + cs2 * 32 + jp);
  unsigned* c1p = (unsigned*)(cB1 + (size_t)browg * 1024 + cs2 * 32 + jp);
  unsigned short* hp = H + (size_t)browg * 256 * 1024 + cs2 * 32 + jp;

  // staging geometry: thread covers rows {4it+strow}, 16B chunk stcc
  const int strow = tid >> 7;            // 0..3
  const int stcc  = tid & 127;           // 0..127

  for (int t = 0; t < 256; ++t) {
    // ---- RMW-free flag barrier: wait until all 32 producer WGs signed t ----
    {
      unsigned v = __hip_atomic_load(fl + (lane & 31), __ATOMIC_RELAXED,
                                     __HIP_MEMORY_SCOPE_AGENT);
      while (!__all(v >= (unsigned)t)) {
        __builtin_amdgcn_s_sleep(1);
        v = __hip_atomic_load(fl + (lane & 31), __ATOMIC_RELAXED,
                              __HIP_MEMORY_SCOPE_AGENT);
      }
    }

    const unsigned short* cinq = ((t & 1) ? cB1 : cB0) + (size_t)mq * 32 * 1024;

    // x-contribution (8 gate preacts, 16B) — issue early, plain cached
    bf16x8 xw = *(const bf16x8*)(xwp + (size_t)t * 4096);

    // ---- stage A-tile [32][1024] bf16: coherent loads -> regs -> LDS (swz) ----
    u32x4 st[8];
#pragma unroll
    for (int it = 0; it < 8; ++it) {
      const void* p = cinq + (size_t)(it * 4 + strow) * 1024 + stcc * 8;
      asm volatile("global_load_dwordx4 %0, %1, off sc0 sc1"
                   : "=&v"(st[it]) : "v"(p) : "memory");
    }
    asm volatile("s_waitcnt vmcnt(0)" ::: "memory");
    __builtin_amdgcn_sched_barrier(0);
#pragma unroll
    for (int it = 0; it < 8; ++it) {
      int r = it * 4 + strow;
      *(u32x4*)&sA[r * 2048 + ((stcc ^ (r & 7)) << 4)] = st[it];
    }
    __syncthreads();   // sA ready

    // ---- GEMM: 2 m-tiles x 16 cols per wave, K=1024; A LDS(swz), B regs ----
    f32x4 acc0 = (f32x4){0.f, 0.f, 0.f, 0.f};
    f32x4 acc1 = (f32x4){0.f, 0.f, 0.f, 0.f};
#pragma unroll
    for (int ks = 0; ks < 32; ++ks) {
      int c2 = ((ch + ks * 4) ^ r7) << 4;
      bf16x8 a0 = *(const bf16x8*)&sA[r0 * 2048 + c2];
      bf16x8 a1 = *(const bf16x8*)&sA[(r0 + 16) * 2048 + c2];
      acc0 = MFMA(a0, bfr[ks], acc0);
      acc1 = MFMA(a1, bfr[ks], acc1);
    }

    // ---- redistribute preacts via LDS ----
#pragma unroll
    for (int rr = 0; rr < 4; ++rr) {
      sP[(ch * 4 + rr) * 132 + nh * 16 + r0]      = acc0[rr];
      sP[(ch * 4 + rr + 16) * 132 + nh * 16 + r0] = acc1[rr];
    }
    __syncthreads();   // sP ready

    float4 g0 = *(const float4*)&sP[b_local * 132 + jp * 4];
    float4 g1 = *(const float4*)&sP[b_local * 132 + jp * 4 + 4];

    // ---- elementwise for 2 cells ----
    float c2a, c2b, ha, hb;
    {
      float pf = g0.x + b2f((unsigned short)xw[0]);
      float pi = g0.y + b2f((unsigned short)xw[1]);
      float pg = g0.z + b2f((unsigned short)xw[2]);
      float po = g0.w + b2f((unsigned short)xw[3]);
      float f = sigmoidf_(pf), i1 = sigmoidf_(pi), gg = tanhf_(pg), o = sigmoidf_(po);
      c2a = cf0 * f + i1 * gg; cf0 = c2a; ha = o * tanhf_(c2a);
    }
    {
      float pf = g1.x + b2f((unsigned short)xw[4]);
      float pi = g1.y + b2f((unsigned short)xw[5]);
      float pg = g1.z + b2f((unsigned short)xw[6]);
      float po = g1.w + b2f((unsigned short)xw[7]);
      float f = sigmoidf_(pf), i1 = sigmoidf_(pi), gg = tanhf_(pg), o = sigmoidf_(po);
      c2b = cf1 * f + i1 * gg; cf1 = c2b; hb = o * tanhf_(c2b);
    }

    // cell: agent-scope atomic store (write-through to MALL, chip-coherent)
    unsigned cw = (unsigned)f2b(c2a) | ((unsigned)f2b(c2b) << 16);
    __hip_atomic_store((t & 1) ? c0p : c1p, cw,
                       __ATOMIC_RELAXED, __HIP_MEMORY_SCOPE_AGENT);
    // h: plain cached store (consumed after kernel end)
    unsigned hw = (unsigned)f2b(ha) | ((unsigned)f2b(hb) << 16);
    *(unsigned*)(hp + (size_t)t * 1024) = hw;

    // ---- signal: drain (syncthreads emits vmcnt(0) per wave) then own-flag ----
    __syncthreads();   // all 512 threads' cell stores are at MALL
    if (tid == 0)
      __hip_atomic_store(fl + cs2, (unsigned)(t + 1),
                         __ATOMIC_RELAXED, __HIP_MEMORY_SCOPE_AGENT);
  }

  // final f32 cell state from registers (kernel-end flush covers it)
  *(float2*)(cellOut + (size_t)browg * 1024 + cs2 * 32 + jp) = make_float2(cf0, cf1);
}

// ---------- launcher ----------
extern "C" void kernel_launch(void* const* d_in, const int* in_sizes, int n_in,
                              void* d_out, int out_size, void* d_ws, size_t ws_size,
                              hipStream_t stream) {
  const float* x   = (const float*)d_in[0];
  const float* Wf  = (const float*)d_in[1];
  const float* bfv = (const float*)d_in[2];
  const float* Wi1 = (const float*)d_in[3];
  const float* bi1 = (const float*)d_in[4];
  const float* Wi2 = (const float*)d_in[5];
  const float* bi2 = (const float*)d_in[6];
  const float* Wo  = (const float*)d_in[7];
  const float* bo  = (const float*)d_in[8];
  const float* Wc  = (const float*)d_in[9];
  const float* bc  = (const float*)d_in[10];
  float* out = (float*)d_out;

  if (ws_size < WS_NEEDED) return;  // visible failure instead of corruption

  char* ws = (char*)d_ws;
  unsigned short* xb      = (unsigned short*)(ws + OFF_XB);
  unsigned short* WhT     = (unsigned short*)(ws + OFF_WHT);
  unsigned short* WxT     = (unsigned short*)(ws + OFF_WXT);
  unsigned short* WcT     = (unsigned short*)(ws + OFF_WCT);
  float*          biasAll = (float*)(ws + OFF_BIAS);
  unsigned short* XW      = (unsigned short*)(ws + OFF_XW);
  unsigned short* H       = (unsigned short*)(ws + OFF_H);
  unsigned short* cB0     = (unsigned short*)(ws + OFF_CB);
  unsigned short* cB1     = (unsigned short*)(ws + OFF_CB + (size_t)128 * 1024 * 2);
  unsigned*       barLn   = (unsigned*)(ws + OFF_BAR);
  float*          cellOut = out + (size_t)32768 * 1024;

  hipMemsetAsync(cB0, 0, (size_t)128 * 1024 * 2, stream);
  hipMemsetAsync(barLn, 0, 16384, stream);    // reset flags EVERY launch

  cvt_x_kernel <<<32768, 256, 0, stream>>>(x, xb);
  cvt_w_kernel <<< 1024, 256, 0, stream>>>(Wf, Wi1, Wi2, Wo, WhT, WxT);
  bias_kernel  <<<   16, 256, 0, stream>>>(bfv, bi1, bi2, bo, biasAll);
  cvt_wc_kernel<<< 4096, 256, 0, stream>>>(Wc, WcT);

  // XW = x @ Wx_all + biases   (M=32768, N=4096, K=1024), bf16 out
  gemm_bt<false><<<dim3(32, 256), 256, 0, stream>>>(xb, WxT, biasAll, XW, 32768, 4096, 1024);

  // persistent recurrence: 128 WGs x 512 threads, cooperative
  {
    void* args[] = { (void*)&WhT, (void*)&XW, (void*)&H,
                     (void*)&cB0, (void*)&cB1, (void*)&cellOut, (void*)&barLn };
    hipLaunchCooperativeKernel(lstm_persist, dim3(128), dim3(512), args, 0u, stream);
  }

  // output_sequence = h @ Wc + bc  (M=32768, N=1024, K=1024), f32 out
  gemm_bt<true><<<dim3(8, 256), 256, 0, stream>>>(H, WcT, bc, out, 32768, 1024, 1024);
}

// Round 11
// 2054.918 us; speedup vs baseline: 1.0097x; 1.0097x over previous
//
#include <hip/hip_runtime.h>
#include <cstdint>
#include <cstddef>

#define DEVINL __device__ __forceinline__

typedef __attribute__((ext_vector_type(8))) short bf16x8;
typedef __attribute__((ext_vector_type(4))) float f32x4;
typedef __attribute__((ext_vector_type(4))) unsigned short u16x4;
typedef __attribute__((ext_vector_type(4))) unsigned int u32x4;

// ---------- workspace layout ----------
static constexpr size_t OFF_XB   = 0;                              // x bf16 [32768][1024]
static constexpr size_t OFF_WHT  = OFF_XB  + (size_t)32768*1024*2; // Wh^T bf16 [4096][1024]
static constexpr size_t OFF_WXT  = OFF_WHT + (size_t)4096*1024*2;  // Wx^T bf16 [4096][1024]
static constexpr size_t OFF_WCT  = OFF_WXT + (size_t)4096*1024*2;  // Wc^T bf16 [1024][1024]
static constexpr size_t OFF_BIAS = OFF_WCT + (size_t)1024*1024*2;  // bias_all f32 [4096]
static constexpr size_t OFF_XW   = OFF_BIAS + 4096*4;              // XW bf16 [32768][4096]
static constexpr size_t OFF_H    = OFF_XW  + (size_t)32768*4096*2; // h bf16 [32768][1024]
static constexpr size_t OFF_CB   = OFF_H   + (size_t)32768*1024*2; // cell bf16 x2 [128][1024]
static constexpr size_t OFF_BAR  = OFF_CB  + (size_t)2*128*1024*2; // flag lines, 16 KB
static constexpr size_t WS_NEEDED = OFF_BAR + 16384;

// ---------- helpers ----------
DEVINL unsigned short f2b(float f) {
  union { float f; unsigned u; } v; v.f = f;
  unsigned r = (v.u + 0x7FFFu + ((v.u >> 16) & 1u)) >> 16;  // RNE
  return (unsigned short)r;
}
DEVINL float b2f(unsigned short h) {
  union { unsigned u; float f; } v; v.u = ((unsigned)h) << 16;
  return v.f;
}
DEVINL float sigmoidf_(float x) { return 1.0f / (1.0f + __expf(-x)); }
DEVINL float tanhf_(float x) { float e = __expf(2.0f * x); return 1.0f - 2.0f / (e + 1.0f); }
DEVINL f32x4 MFMA(bf16x8 a, bf16x8 b, f32x4 c) {
  return __builtin_amdgcn_mfma_f32_16x16x32_bf16(a, b, c, 0, 0, 0);
}
DEVINL void gload16(const void* g, void* l) {
  __builtin_amdgcn_global_load_lds(
      (const __attribute__((address_space(1))) void*)g,
      (__attribute__((address_space(3))) void*)l, 16, 0, 0);
}

// ---------- conversions ----------
__global__ void cvt_x_kernel(const float* __restrict__ x, unsigned short* __restrict__ xb) {
  size_t i = ((size_t)blockIdx.x * 256 + threadIdx.x) * 4;
  float4 v = *(const float4*)(x + i);
  u16x4 o; o.x = f2b(v.x); o.y = f2b(v.y); o.z = f2b(v.z); o.w = f2b(v.w);
  *(u16x4*)(xb + i) = o;
}

// coalesced transpose-convert via 64x64 LDS tile (proven r8)
__global__ __launch_bounds__(256)
void cvt_w_kernel(const float* __restrict__ Wf, const float* __restrict__ Wi1,
                  const float* __restrict__ Wi2, const float* __restrict__ Wo,
                  unsigned short* __restrict__ WhT, unsigned short* __restrict__ WxT) {
  __shared__ float tile[64][65];
  const int bid = blockIdx.x;          // 16 jt x 16 kt x 4 g = 1024 blocks
  const int g  = bid & 3;
  const int kt = (bid >> 2) & 15;
  const int jt = bid >> 6;
  const float* W = (g == 0) ? Wf : (g == 1) ? Wi1 : (g == 2) ? Wi2 : Wo;
  const int tid = threadIdx.x;
  const int jj  = tid & 63;
  const int kr  = tid >> 6;            // 0..3

  for (int h = 0; h < 2; ++h) {
    const float* Wb = W + (size_t)(h ? 1024 : 0) * 1024;
#pragma unroll
    for (int i = 0; i < 16; ++i) {
      int kl = i * 4 + kr;
      tile[kl][jj] = Wb[(size_t)(kt * 64 + kl) * 1024 + jt * 64 + jj];
    }
    __syncthreads();
    unsigned short* Out = h ? WxT : WhT;
    unsigned short* op  = Out + (size_t)(4 * (jt * 64 + jj) + g) * 1024 + kt * 64 + kr * 16;
#pragma unroll
    for (int q = 0; q < 4; ++q) {
      u16x4 v;
#pragma unroll
      for (int e = 0; e < 4; ++e)
        ((unsigned short*)&v)[e] = f2b(tile[kr * 16 + q * 4 + e][jj]);
      *(u16x4*)(op + q * 4) = v;
    }
    __syncthreads();
  }
}

__global__ void bias_kernel(const float* __restrict__ bf_, const float* __restrict__ bi1,
                            const float* __restrict__ bi2, const float* __restrict__ bo,
                            float* __restrict__ biasAll) {
  int gc = blockIdx.x * 256 + threadIdx.x;   // 4096
  int j = gc >> 2, g = gc & 3;
  const float* bb = (g == 0) ? bf_ : (g == 1) ? bi1 : (g == 2) ? bi2 : bo;
  biasAll[gc] = bb[j];
}

__global__ void cvt_wc_kernel(const float* __restrict__ Wc, unsigned short* __restrict__ WcT) {
  int idx = blockIdx.x * 256 + threadIdx.x;   // 1024*1024 total
  int k = idx & 1023, n = idx >> 10;
  WcT[idx] = f2b(Wc[(size_t)k * 1024 + n]);
}

// ---------- 128x128 bf16 GEMM, B as B^T [N][K], C = A@B + bias ----------
template<bool OUT_F32>
__global__ __launch_bounds__(256)
void gemm_bt(const unsigned short* __restrict__ A,
             const unsigned short* __restrict__ Bt,
             const float* __restrict__ bias,
             void* __restrict__ C,
             int M, int N, int K) {
  __shared__ unsigned short sA[128 * 64];
  __shared__ unsigned short sB[128 * 64];
  const int tid  = threadIdx.x;
  const int lane = tid & 63;
  const int wid  = tid >> 6;

  // bijective XCD swizzle (grids are %8==0)
  const int nwg = gridDim.x * gridDim.y;
  const int lin = blockIdx.y * gridDim.x + blockIdx.x;
  const int cpx = nwg >> 3;
  const int swz = (lin & 7) * cpx + (lin >> 3);
  const int m0  = (swz / gridDim.x) * 128;
  const int n0  = (swz % gridDim.x) * 128;

  const int wm = (wid >> 1) * 64;
  const int wn = (wid & 1) * 64;

  f32x4 acc[4][4];
#pragma unroll
  for (int i = 0; i < 4; ++i)
#pragma unroll
    for (int j = 0; j < 4; ++j) acc[i][j] = (f32x4){0.f, 0.f, 0.f, 0.f};

  for (int k0 = 0; k0 < K; k0 += 64) {
#pragma unroll
    for (int p = 0; p < 4; ++p) {
      int t = p * 256 + tid;
      int r = t >> 3, c = t & 7;
      gload16(A  + (size_t)(m0 + r) * K + k0 + c * 8, (char*)sA + p * 4096 + wid * 1024);
      gload16(Bt + (size_t)(n0 + r) * K + k0 + c * 8, (char*)sB + p * 4096 + wid * 1024);
    }
    __syncthreads();
#pragma unroll
    for (int kk = 0; kk < 2; ++kk) {
      bf16x8 av[4], bv[4];
#pragma unroll
      for (int mi = 0; mi < 4; ++mi)
        av[mi] = *(const bf16x8*)&sA[(wm + mi * 16 + (lane & 15)) * 64 + kk * 32 + (lane >> 4) * 8];
#pragma unroll
      for (int ni = 0; ni < 4; ++ni)
        bv[ni] = *(const bf16x8*)&sB[(wn + ni * 16 + (lane & 15)) * 64 + kk * 32 + (lane >> 4) * 8];
#pragma unroll
      for (int mi = 0; mi < 4; ++mi)
#pragma unroll
        for (int ni = 0; ni < 4; ++ni)
          acc[mi][ni] = MFMA(av[mi], bv[ni], acc[mi][ni]);
    }
    __syncthreads();
  }

#pragma unroll
  for (int mi = 0; mi < 4; ++mi)
#pragma unroll
    for (int ni = 0; ni < 4; ++ni)
#pragma unroll
      for (int r = 0; r < 4; ++r) {
        int row = m0 + wm + mi * 16 + (lane >> 4) * 4 + r;
        int col = n0 + wn + ni * 16 + (lane & 15);
        float v = acc[mi][ni][r] + bias[col];
        if (OUT_F32) ((float*)C)[(size_t)row * N + col] = v;
        else ((unsigned short*)C)[(size_t)row * N + col] = f2b(v);
      }
}

// ---------- persistent recurrence v11: r7 envelope + RMW-free flag barrier ----------
// 256 WGs x 512 threads (r7-proven coop envelope, 1097us). WG (mq, cs):
// mq=wgid&3 -> rows 32mq..+32 (4 independent quarters); cs=wgid>>2 (0..63) ->
// gate-cols 64cs..+64. Wave (mh,nh): one 16x16 MFMA tile. MALL protocol
// identical to r5/r7: cell stores = relaxed agent atomics (write-through);
// cell loads = sc0|sc1 asm; H plain cached; no cache-maintenance fences.
// ONLY change vs r7: barrier. Per quarter, 64 flag words (one per WG).
// Leader STOREs epoch t+1 to its OWN flag after the vmcnt-draining
// __syncthreads (no RMW -> no serialization); at top of step t wave 0 polls
// all 64 flags (lane L watches flag L) until >= t, then __syncthreads
// releases the WG. Correctness of this flag protocol proven in r9.
__global__ __launch_bounds__(512, 2)
void lstm_persist(const unsigned short* __restrict__ WhT,  // [4096][1024] bf16
                  const unsigned short* __restrict__ XW,   // [32768][4096] bf16
                  unsigned short* __restrict__ H,          // [32768][1024] bf16
                  unsigned short* __restrict__ cB0,        // [128][1024] bf16
                  unsigned short* __restrict__ cB1,
                  float* __restrict__ cellOut,             // [128][1024] f32
                  unsigned* __restrict__ bar) {
  __shared__ __align__(16) char  sA[32 * 2064];   // A-tile, padded stride (r7)
  __shared__ __align__(16) float sP[32 * 68];     // preact redistribute

  const int tid  = threadIdx.x;
  const int lane = tid & 63;
  const int wid  = tid >> 6;       // 0..7
  const int mh   = wid >> 2;       // m-tile 0..1
  const int nh   = wid & 3;        // n-tile 0..3
  const int wgid = blockIdx.x;
  const int mq   = wgid & 3;       // row quarter
  const int cs   = wgid >> 2;      // col slice 0..63

  unsigned* fl = bar + mq * 64;    // 64 flags per quarter (256B region)

  const int r0 = lane & 15;        // row/col within tile
  const int ch = lane >> 4;        // 16B chunk id within K-slice

  // ---- Wh fragments in registers: volatile loads (non-remat), 128 regs ----
  bf16x8 bfr[32];
  {
    const unsigned short* bp = WhT + (size_t)(cs * 64 + nh * 16 + r0) * 1024 + ch * 8;
#pragma unroll
    for (int ks = 0; ks < 32; ++ks)
      bfr[ks] = *(const volatile bf16x8*)(bp + ks * 32);
  }

  // ---- per-thread cell ownership (threads 0..255 only): 2 cell cols ----
  const int b_local = (tid & 255) >> 3;  // 0..31
  const int jp      = (tid & 7) * 2;     // 0,2,..,14
  const int browg   = mq * 32 + b_local; // global batch row
  float cf0 = 0.f, cf1 = 0.f;

  const unsigned short* xwp = XW + (size_t)browg * 256 * 4096 + cs * 64 + jp * 4;
  unsigned* c0p = (unsigned*)(cB0 + (size_t)browg * 1024 + cs * 16 + jp);
  unsigned* c1p = (unsigned*)(cB1 + (size_t)browg * 1024 + cs * 16 + jp);
  unsigned short* hp = H + (size_t)browg * 256 * 1024 + cs * 16 + jp;

  // staging geometry: thread covers rows {4it+strow}, 16B chunk stcc
  const int strow = tid >> 7;            // 0..3
  const int stcc  = tid & 127;           // 0..127

  for (int t = 0; t < 256; ++t) {
    // ---- flag wait: all 64 quarter WGs have signed step t-1 ----
    if (tid < 64) {
      unsigned v = __hip_atomic_load(fl + lane, __ATOMIC_RELAXED,
                                     __HIP_MEMORY_SCOPE_AGENT);
      while (!__all(v >= (unsigned)t)) {
        __builtin_amdgcn_s_sleep(1);
        v = __hip_atomic_load(fl + lane, __ATOMIC_RELAXED,
                              __HIP_MEMORY_SCOPE_AGENT);
      }
    }
    __syncthreads();   // release all 8 waves

    const unsigned short* cinq = ((t & 1) ? cB1 : cB0) + (size_t)mq * 32 * 1024;

    // x-contribution (8 gate preacts, 16B) — plain cached, tid<256
    bf16x8 xw;
    if (tid < 256) xw = *(const bf16x8*)(xwp + (size_t)t * 4096);

    // ---- stage A-tile [32][1024] bf16: coherent loads -> regs -> LDS ----
    u32x4 st[8];
#pragma unroll
    for (int it = 0; it < 8; ++it) {
      const void* p = cinq + (size_t)(it * 4 + strow) * 1024 + stcc * 8;
      asm volatile("global_load_dwordx4 %0, %1, off sc0 sc1"
                   : "=&v"(st[it]) : "v"(p) : "memory");
    }
    asm volatile("s_waitcnt vmcnt(0)" ::: "memory");
    __builtin_amdgcn_sched_barrier(0);
#pragma unroll
    for (int it = 0; it < 8; ++it) {
      int r = it * 4 + strow;
      *(u32x4*)&sA[r * 2064 + stcc * 16] = st[it];
    }
    __syncthreads();   // sA ready

    // ---- GEMM: one 16x16 tile per wave, K=1024; A LDS, B regs ----
    f32x4 acc = (f32x4){0.f, 0.f, 0.f, 0.f};
#pragma unroll
    for (int ks = 0; ks < 32; ++ks) {
      bf16x8 a0 = *(const bf16x8*)&sA[(mh * 16 + r0) * 2064 + (ch + ks * 4) * 16];
      acc = MFMA(a0, bfr[ks], acc);
    }

    // ---- redistribute preacts via LDS ----
#pragma unroll
    for (int rr = 0; rr < 4; ++rr)
      sP[(mh * 16 + ch * 4 + rr) * 68 + nh * 16 + r0] = acc[rr];
    __syncthreads();   // sP ready

    if (tid < 256) {
      float4 g0 = *(const float4*)&sP[b_local * 68 + jp * 4];
      float4 g1 = *(const float4*)&sP[b_local * 68 + jp * 4 + 4];

      // ---- elementwise for 2 cells ----
      float c2a, c2b, ha, hb;
      {
        float pf = g0.x + b2f((unsigned short)xw[0]);
        float pi = g0.y + b2f((unsigned short)xw[1]);
        float pg = g0.z + b2f((unsigned short)xw[2]);
        float po = g0.w + b2f((unsigned short)xw[3]);
        float f = sigmoidf_(pf), i1 = sigmoidf_(pi), gg = tanhf_(pg), o = sigmoidf_(po);
        c2a = cf0 * f + i1 * gg; cf0 = c2a; ha = o * tanhf_(c2a);
      }
      {
        float pf = g1.x + b2f((unsigned short)xw[4]);
        float pi = g1.y + b2f((unsigned short)xw[5]);
        float pg = g1.z + b2f((unsigned short)xw[6]);
        float po = g1.w + b2f((unsigned short)xw[7]);
        float f = sigmoidf_(pf), i1 = sigmoidf_(pi), gg = tanhf_(pg), o = sigmoidf_(po);
        c2b = cf1 * f + i1 * gg; cf1 = c2b; hb = o * tanhf_(c2b);
      }

      // cell: agent-scope atomic store (write-through to MALL, chip-coherent)
      unsigned cw = (unsigned)f2b(c2a) | ((unsigned)f2b(c2b) << 16);
      __hip_atomic_store((t & 1) ? c0p : c1p, cw,
                         __ATOMIC_RELAXED, __HIP_MEMORY_SCOPE_AGENT);
      // h: plain cached store (consumed after kernel end)
      unsigned hw = (unsigned)f2b(ha) | ((unsigned)f2b(hb) << 16);
      *(unsigned*)(hp + (size_t)t * 1024) = hw;
    }

    // ---- signal: drain (syncthreads emits vmcnt(0) per wave) then own flag ----
    __syncthreads();   // all threads' cell stores are at MALL
    if (tid == 0)
      __hip_atomic_store(fl + cs, (unsigned)(t + 1),
                         __ATOMIC_RELAXED, __HIP_MEMORY_SCOPE_AGENT);
  }

  // final f32 cell state from registers (kernel-end flush covers it)
  if (tid < 256)
    *(float2*)(cellOut + (size_t)browg * 1024 + cs * 16 + jp) = make_float2(cf0, cf1);
}

// ---------- launcher ----------
extern "C" void kernel_launch(void* const* d_in, const int* in_sizes, int n_in,
                              void* d_out, int out_size, void* d_ws, size_t ws_size,
                              hipStream_t stream) {
  const float* x   = (const float*)d_in[0];
  const float* Wf  = (const float*)d_in[1];
  const float* bfv = (const float*)d_in[2];
  const float* Wi1 = (const float*)d_in[3];
  const float* bi1 = (const float*)d_in[4];
  const float* Wi2 = (const float*)d_in[5];
  const float* bi2 = (const float*)d_in[6];
  const float* Wo  = (const float*)d_in[7];
  const float* bo  = (const float*)d_in[8];
  const float* Wc  = (const float*)d_in[9];
  const float* bc  = (const float*)d_in[10];
  float* out = (float*)d_out;

  if (ws_size < WS_NEEDED) return;  // visible failure instead of corruption

  char* ws = (char*)d_ws;
  unsigned short* xb      = (unsigned short*)(ws + OFF_XB);
  unsigned short* WhT     = (unsigned short*)(ws + OFF_WHT);
  unsigned short* WxT     = (unsigned short*)(ws + OFF_WXT);
  unsigned short* WcT     = (unsigned short*)(ws + OFF_WCT);
  float*          biasAll = (float*)(ws + OFF_BIAS);
  unsigned short* XW      = (unsigned short*)(ws + OFF_XW);
  unsigned short* H       = (unsigned short*)(ws + OFF_H);
  unsigned short* cB0     = (unsigned short*)(ws + OFF_CB);
  unsigned short* cB1     = (unsigned short*)(ws + OFF_CB + (size_t)128 * 1024 * 2);
  unsigned*       barLn   = (unsigned*)(ws + OFF_BAR);
  float*          cellOut = out + (size_t)32768 * 1024;

  hipMemsetAsync(cB0, 0, (size_t)128 * 1024 * 2, stream);
  hipMemsetAsync(barLn, 0, 16384, stream);    // reset flags EVERY launch

  cvt_x_kernel <<<32768, 256, 0, stream>>>(x, xb);
  cvt_w_kernel <<< 1024, 256, 0, stream>>>(Wf, Wi1, Wi2, Wo, WhT, WxT);
  bias_kernel  <<<   16, 256, 0, stream>>>(bfv, bi1, bi2, bo, biasAll);
  cvt_wc_kernel<<< 4096, 256, 0, stream>>>(Wc, WcT);

  // XW = x @ Wx_all + biases   (M=32768, N=4096, K=1024), bf16 out
  gemm_bt<false><<<dim3(32, 256), 256, 0, stream>>>(xb, WxT, biasAll, XW, 32768, 4096, 1024);

  // persistent recurrence: 256 WGs x 512 threads (proven envelope), cooperative
  {
    void* args[] = { (void*)&WhT, (void*)&XW, (void*)&H,
                     (void*)&cB0, (void*)&cB1, (void*)&cellOut, (void*)&barLn };
    hipLaunchCooperativeKernel(lstm_persist, dim3(256), dim3(512), args, 0u, stream);
  }

  // output_sequence = h @ Wc + bc  (M=32768, N=1024, K=1024), f32 out
  gemm_bt<true><<<dim3(8, 256), 256, 0, stream>>>(H, WcT, bc, out, 32768, 1024, 1024);
}

// Round 12
// 1500.641 us; speedup vs baseline: 1.3826x; 1.3694x over previous
//
#include <hip/hip_runtime.h>
#include <cstdint>
#include <cstddef>

#define DEVINL __device__ __forceinline__

typedef __attribute__((ext_vector_type(8))) short bf16x8;
typedef __attribute__((ext_vector_type(4))) float f32x4;
typedef __attribute__((ext_vector_type(4))) unsigned short u16x4;
typedef __attribute__((ext_vector_type(4))) unsigned int u32x4;

// ---------- workspace layout ----------
static constexpr size_t OFF_XB   = 0;                              // x bf16 [32768][1024]
static constexpr size_t OFF_WHT  = OFF_XB  + (size_t)32768*1024*2; // Wh^T bf16 [4096][1024]
static constexpr size_t OFF_WXT  = OFF_WHT + (size_t)4096*1024*2;  // Wx^T bf16 [4096][1024]
static constexpr size_t OFF_WCT  = OFF_WXT + (size_t)4096*1024*2;  // Wc^T bf16 [1024][1024]
static constexpr size_t OFF_BIAS = OFF_WCT + (size_t)1024*1024*2;  // bias_all f32 [4096]
static constexpr size_t OFF_XW   = OFF_BIAS + 4096*4;              // XW bf16 [32768][4096]
static constexpr size_t OFF_H    = OFF_XW  + (size_t)32768*4096*2; // h bf16 [32768][1024]
static constexpr size_t OFF_CB   = OFF_H   + (size_t)32768*1024*2; // cell bf16 x2 [128][1024]
static constexpr size_t OFF_BAR  = OFF_CB  + (size_t)2*128*1024*2; // barrier lines, 16 KB
static constexpr size_t WS_NEEDED = OFF_BAR + 16384;

// ---------- helpers ----------
DEVINL unsigned short f2b(float f) {
  union { float f; unsigned u; } v; v.f = f;
  unsigned r = (v.u + 0x7FFFu + ((v.u >> 16) & 1u)) >> 16;  // RNE
  return (unsigned short)r;
}
DEVINL float b2f(unsigned short h) {
  union { unsigned u; float f; } v; v.u = ((unsigned)h) << 16;
  return v.f;
}
DEVINL float sigmoidf_(float x) { return 1.0f / (1.0f + __expf(-x)); }
DEVINL float tanhf_(float x) { float e = __expf(2.0f * x); return 1.0f - 2.0f / (e + 1.0f); }
DEVINL f32x4 MFMA(bf16x8 a, bf16x8 b, f32x4 c) {
  return __builtin_amdgcn_mfma_f32_16x16x32_bf16(a, b, c, 0, 0, 0);
}
DEVINL void gload16(const void* g, void* l) {
  __builtin_amdgcn_global_load_lds(
      (const __attribute__((address_space(1))) void*)g,
      (__attribute__((address_space(3))) void*)l, 16, 0, 0);
}

// ---------- conversions ----------
__global__ void cvt_x_kernel(const float* __restrict__ x, unsigned short* __restrict__ xb) {
  size_t i = ((size_t)blockIdx.x * 256 + threadIdx.x) * 4;
  float4 v = *(const float4*)(x + i);
  u16x4 o; o.x = f2b(v.x); o.y = f2b(v.y); o.z = f2b(v.z); o.w = f2b(v.w);
  *(u16x4*)(xb + i) = o;
}

// coalesced transpose-convert via 64x64 LDS tile (proven r8)
__global__ __launch_bounds__(256)
void cvt_w_kernel(const float* __restrict__ Wf, const float* __restrict__ Wi1,
                  const float* __restrict__ Wi2, const float* __restrict__ Wo,
                  unsigned short* __restrict__ WhT, unsigned short* __restrict__ WxT) {
  __shared__ float tile[64][65];
  const int bid = blockIdx.x;          // 16 jt x 16 kt x 4 g = 1024 blocks
  const int g  = bid & 3;
  const int kt = (bid >> 2) & 15;
  const int jt = bid >> 6;
  const float* W = (g == 0) ? Wf : (g == 1) ? Wi1 : (g == 2) ? Wi2 : Wo;
  const int tid = threadIdx.x;
  const int jj  = tid & 63;
  const int kr  = tid >> 6;            // 0..3

  for (int h = 0; h < 2; ++h) {
    const float* Wb = W + (size_t)(h ? 1024 : 0) * 1024;
#pragma unroll
    for (int i = 0; i < 16; ++i) {
      int kl = i * 4 + kr;
      tile[kl][jj] = Wb[(size_t)(kt * 64 + kl) * 1024 + jt * 64 + jj];
    }
    __syncthreads();
    unsigned short* Out = h ? WxT : WhT;
    unsigned short* op  = Out + (size_t)(4 * (jt * 64 + jj) + g) * 1024 + kt * 64 + kr * 16;
#pragma unroll
    for (int q = 0; q < 4; ++q) {
      u16x4 v;
#pragma unroll
      for (int e = 0; e < 4; ++e)
        ((unsigned short*)&v)[e] = f2b(tile[kr * 16 + q * 4 + e][jj]);
      *(u16x4*)(op + q * 4) = v;
    }
    __syncthreads();
  }
}

__global__ void bias_kernel(const float* __restrict__ bf_, const float* __restrict__ bi1,
                            const float* __restrict__ bi2, const float* __restrict__ bo,
                            float* __restrict__ biasAll) {
  int gc = blockIdx.x * 256 + threadIdx.x;   // 4096
  int j = gc >> 2, g = gc & 3;
  const float* bb = (g == 0) ? bf_ : (g == 1) ? bi1 : (g == 2) ? bi2 : bo;
  biasAll[gc] = bb[j];
}

__global__ void cvt_wc_kernel(const float* __restrict__ Wc, unsigned short* __restrict__ WcT) {
  int idx = blockIdx.x * 256 + threadIdx.x;   // 1024*1024 total
  int k = idx & 1023, n = idx >> 10;
  WcT[idx] = f2b(Wc[(size_t)k * 1024 + n]);
}

// ---------- 256x256 pipelined bf16 GEMM (T2 swizzle + T4 counted vmcnt) ----------
// 512 thr = 8 waves (2M x 4N). BK=32; 4 single-K-tile LDS buffers (A16K+B16K
// each = 128 KB); tile t lives in buf t&3; during group g we stage tile g+3
// (into buf (g-1)&3, freed at group g-1 end). vmcnt(8) at group end keeps
// 2 tiles in flight (never drains to 0 mid-loop). Swizzle: 16B chunk c of
// row r stored at linear slot, source chunk = c ^ ((r>>1)&3); ds_read applies
// the same XOR -> 16 lanes hit 8 distinct 16B slots per 128B window (2-way,
// free). B given as B^T [N][K]. C = A@B + bias.
template<bool OUT_F32>
__global__ __launch_bounds__(512, 2)
void gemm_bt(const unsigned short* __restrict__ A,
             const unsigned short* __restrict__ Bt,
             const float* __restrict__ bias,
             void* __restrict__ C,
             int M, int N, int K) {
  __shared__ char sT[4][32768];        // per buf: A[256][32] @0, B[256][32] @16384
  const int tid  = threadIdx.x;
  const int lane = tid & 63;
  const int wid  = tid >> 6;
  const int wm   = (wid >> 2) * 128;   // 2 m-waves
  const int wn   = (wid & 3) * 64;     // 4 n-waves

  // bijective XCD swizzle (grids are %8==0)
  const int nwg = gridDim.x * gridDim.y;
  const int lin = blockIdx.y * gridDim.x + blockIdx.x;
  const int cpx = nwg >> 3;
  const int swz = (lin & 7) * cpx + (lin >> 3);
  const int m0  = (swz / gridDim.x) * 256;
  const int n0  = (swz % gridDim.x) * 256;

  const int nt = K >> 5;               // K-tiles of 32

  f32x4 acc[8][4];
#pragma unroll
  for (int i = 0; i < 8; ++i)
#pragma unroll
    for (int j = 0; j < 4; ++j) acc[i][j] = (f32x4){0.f, 0.f, 0.f, 0.f};

  // stage one K-tile's A (or B) into buf: 2 x gload16 per thread
  auto stageA = [&](int kt, int buf) {
#pragma unroll
    for (int l = 0; l < 2; ++l) {
      int s = l * 512 + tid;           // slot 0..1023
      int r = s >> 2, c = s & 3;
      int cg = c ^ ((r >> 1) & 3);     // pre-swizzled source chunk
      gload16(A + (size_t)(m0 + r) * K + kt * 32 + cg * 8, sT[buf] + s * 16);
    }
  };
  auto stageB = [&](int kt, int buf) {
#pragma unroll
    for (int l = 0; l < 2; ++l) {
      int s = l * 512 + tid;
      int r = s >> 2, c = s & 3;
      int cg = c ^ ((r >> 1) & 3);
      gload16(Bt + (size_t)(n0 + r) * K + kt * 32 + cg * 8, sT[buf] + 16384 + s * 16);
    }
  };

  // prologue: tiles 0,1,2 (12 loads); wait for tile 0 (oldest 4)
  stageA(0, 0); stageB(0, 0);
  stageA(1, 1); stageB(1, 1);
  stageA(2, 2); stageB(2, 2);
  asm volatile("s_waitcnt vmcnt(8)" ::: "memory");
  __builtin_amdgcn_s_barrier();

  const int ch = lane >> 4;            // 16B chunk 0..3 within K-tile

#pragma unroll 1
  for (int g = 0; g < nt; ++g) {
    const int rb = g & 3;
    const char* ab = sT[rb];
    const char* bb = sT[rb] + 16384;

    // ---- phase 1: read B frags + A mi0-3; stage A(g+3) ----
    bf16x8 bv[4], av[4];
#pragma unroll
    for (int ni = 0; ni < 4; ++ni) {
      int col = wn + ni * 16 + (lane & 15);
      bv[ni] = *(const bf16x8*)(bb + col * 64 + ((ch ^ ((col >> 1) & 3)) << 4));
    }
#pragma unroll
    for (int mi = 0; mi < 4; ++mi) {
      int row = wm + mi * 16 + (lane & 15);
      av[mi] = *(const bf16x8*)(ab + row * 64 + ((ch ^ ((row >> 1) & 3)) << 4));
    }
    if (g + 3 < nt) stageA(g + 3, (g + 3) & 3);
    __builtin_amdgcn_s_barrier();
    __builtin_amdgcn_s_setprio(1);
#pragma unroll
    for (int mi = 0; mi < 4; ++mi)
#pragma unroll
      for (int ni = 0; ni < 4; ++ni)
        acc[mi][ni] = MFMA(av[mi], bv[ni], acc[mi][ni]);
    __builtin_amdgcn_s_setprio(0);
    __builtin_amdgcn_s_barrier();

    // ---- phase 2: read A mi4-7; stage B(g+3) ----
#pragma unroll
    for (int mi = 0; mi < 4; ++mi) {
      int row = wm + 64 + mi * 16 + (lane & 15);
      av[mi] = *(const bf16x8*)(ab + row * 64 + ((ch ^ ((row >> 1) & 3)) << 4));
    }
    if (g + 3 < nt) stageB(g + 3, (g + 3) & 3);
    __builtin_amdgcn_s_barrier();
    __builtin_amdgcn_s_setprio(1);
#pragma unroll
    for (int mi = 0; mi < 4; ++mi)
#pragma unroll
      for (int ni = 0; ni < 4; ++ni)
        acc[mi + 4][ni] = MFMA(av[mi], bv[ni], acc[mi + 4][ni]);
    __builtin_amdgcn_s_setprio(0);

    // ---- group end: counted vmcnt (tile g+1 must be complete) ----
    if (g <= nt - 4)      asm volatile("s_waitcnt vmcnt(8)" ::: "memory");
    else if (g == nt - 3) asm volatile("s_waitcnt vmcnt(4)" ::: "memory");
    else if (g == nt - 2) asm volatile("s_waitcnt vmcnt(0)" ::: "memory");
    __builtin_amdgcn_s_barrier();
  }

  // ---- epilogue ----
#pragma unroll
  for (int mi = 0; mi < 8; ++mi)
#pragma unroll
    for (int ni = 0; ni < 4; ++ni)
#pragma unroll
      for (int r = 0; r < 4; ++r) {
        int row = m0 + wm + mi * 16 + (lane >> 4) * 4 + r;
        int col = n0 + wn + ni * 16 + (lane & 15);
        float v = acc[mi][ni][r] + bias[col];
        if (OUT_F32) ((float*)C)[(size_t)row * N + col] = v;
        else ((unsigned short*)C)[(size_t)row * N + col] = f2b(v);
      }
}

// ---------- persistent recurrence (r7-proven exact: 1097us) ----------
__global__ __launch_bounds__(512, 2)
void lstm_persist(const unsigned short* __restrict__ WhT,  // [4096][1024] bf16
                  const unsigned short* __restrict__ XW,   // [32768][4096] bf16
                  unsigned short* __restrict__ H,          // [32768][1024] bf16
                  unsigned short* __restrict__ cB0,        // [128][1024] bf16
                  unsigned short* __restrict__ cB1,
                  float* __restrict__ cellOut,             // [128][1024] f32
                  unsigned* __restrict__ bar) {
  __shared__ __align__(16) char  sA[32 * 2064];   // A-tile, padded stride
  __shared__ __align__(16) float sP[32 * 68];     // preact redistribute

  const int tid  = threadIdx.x;
  const int lane = tid & 63;
  const int wid  = tid >> 6;       // 0..7
  const int mh   = wid >> 2;       // m-tile 0..1
  const int nh   = wid & 3;        // n-tile 0..3
  const int wgid = blockIdx.x;
  const int mq   = wgid & 3;       // row quarter
  const int cs   = wgid >> 2;      // col slice 0..63
  const int grp  = cs >> 3;        // subgroup 0..7 within quarter

  unsigned* qc   = bar + mq * 64;
  unsigned* qf   = bar + 1024 + mq * 64;
  unsigned* gcnt = bar + 2048 + (mq * 8 + grp) * 64;

  const int r0 = lane & 15;
  const int ch = lane >> 4;

  // Wh fragments (volatile, non-remat) — live in unified RF (AGPR-backed)
  bf16x8 bfr[32];
  {
    const unsigned short* bp = WhT + (size_t)(cs * 64 + nh * 16 + r0) * 1024 + ch * 8;
#pragma unroll
    for (int ks = 0; ks < 32; ++ks)
      bfr[ks] = *(const volatile bf16x8*)(bp + ks * 32);
  }

  const int b_local = (tid & 255) >> 3;  // 0..31
  const int jp      = (tid & 7) * 2;     // 0,2,..,14
  const int browg   = mq * 32 + b_local;
  float cf0 = 0.f, cf1 = 0.f;

  const unsigned short* xwp = XW + (size_t)browg * 256 * 4096 + cs * 64 + jp * 4;
  unsigned* c0p = (unsigned*)(cB0 + (size_t)browg * 1024 + cs * 16 + jp);
  unsigned* c1p = (unsigned*)(cB1 + (size_t)browg * 1024 + cs * 16 + jp);
  unsigned short* hp = H + (size_t)browg * 256 * 1024 + cs * 16 + jp;

  const int strow = tid >> 7;            // 0..3
  const int stcc  = tid & 127;           // 0..127

  for (int t = 0; t < 256; ++t) {
    const unsigned short* cinq = ((t & 1) ? cB1 : cB0) + (size_t)mq * 32 * 1024;

    bf16x8 xw;
    if (tid < 256) xw = *(const bf16x8*)(xwp + (size_t)t * 4096);

    u32x4 st[8];
#pragma unroll
    for (int it = 0; it < 8; ++it) {
      const void* p = cinq + (size_t)(it * 4 + strow) * 1024 + stcc * 8;
      asm volatile("global_load_dwordx4 %0, %1, off sc0 sc1"
                   : "=&v"(st[it]) : "v"(p) : "memory");
    }
    asm volatile("s_waitcnt vmcnt(0)" ::: "memory");
    __builtin_amdgcn_sched_barrier(0);
#pragma unroll
    for (int it = 0; it < 8; ++it) {
      int r = it * 4 + strow;
      *(u32x4*)&sA[r * 2064 + stcc * 16] = st[it];
    }
    __syncthreads();

    f32x4 acc = (f32x4){0.f, 0.f, 0.f, 0.f};
#pragma unroll
    for (int ks = 0; ks < 32; ++ks) {
      bf16x8 a0 = *(const bf16x8*)&sA[(mh * 16 + r0) * 2064 + (ch + ks * 4) * 16];
      acc = MFMA(a0, bfr[ks], acc);
    }

#pragma unroll
    for (int rr = 0; rr < 4; ++rr)
      sP[(mh * 16 + ch * 4 + rr) * 68 + nh * 16 + r0] = acc[rr];
    __syncthreads();

    if (tid < 256) {
      float4 g0 = *(const float4*)&sP[b_local * 68 + jp * 4];
      float4 g1 = *(const float4*)&sP[b_local * 68 + jp * 4 + 4];

      float c2a, c2b, ha, hb;
      {
        float pf = g0.x + b2f((unsigned short)xw[0]);
        float pi = g0.y + b2f((unsigned short)xw[1]);
        float pg = g0.z + b2f((unsigned short)xw[2]);
        float po = g0.w + b2f((unsigned short)xw[3]);
        float f = sigmoidf_(pf), i1 = sigmoidf_(pi), gg = tanhf_(pg), o = sigmoidf_(po);
        c2a = cf0 * f + i1 * gg; cf0 = c2a; ha = o * tanhf_(c2a);
      }
      {
        float pf = g1.x + b2f((unsigned short)xw[4]);
        float pi = g1.y + b2f((unsigned short)xw[5]);
        float pg = g1.z + b2f((unsigned short)xw[6]);
        float po = g1.w + b2f((unsigned short)xw[7]);
        float f = sigmoidf_(pf), i1 = sigmoidf_(pi), gg = tanhf_(pg), o = sigmoidf_(po);
        c2b = cf1 * f + i1 * gg; cf1 = c2b; hb = o * tanhf_(c2b);
      }

      unsigned cw = (unsigned)f2b(c2a) | ((unsigned)f2b(c2b) << 16);
      __hip_atomic_store((t & 1) ? c0p : c1p, cw,
                         __ATOMIC_RELAXED, __HIP_MEMORY_SCOPE_AGENT);
      unsigned hw = (unsigned)f2b(ha) | ((unsigned)f2b(hb) << 16);
      *(unsigned*)(hp + (size_t)t * 1024) = hw;
    }

    __syncthreads();   // vmcnt drain: cell stores at MALL
    if (tid == 0) {
      unsigned tgt = 8u * (unsigned)(t + 1);
      unsigned n = __hip_atomic_fetch_add(gcnt, 1u, __ATOMIC_RELAXED,
                                          __HIP_MEMORY_SCOPE_AGENT);
      if (n == tgt - 1u) {
        unsigned m = __hip_atomic_fetch_add(qc, 1u, __ATOMIC_RELAXED,
                                            __HIP_MEMORY_SCOPE_AGENT);
        if (m == tgt - 1u)
          __hip_atomic_store(qf, (unsigned)(t + 1),
                             __ATOMIC_RELAXED, __HIP_MEMORY_SCOPE_AGENT);
      }
      while (__hip_atomic_load(qf, __ATOMIC_RELAXED, __HIP_MEMORY_SCOPE_AGENT)
             < (unsigned)(t + 1))
        __builtin_amdgcn_s_sleep(1);
    }
    __syncthreads();
  }

  if (tid < 256)
    *(float2*)(cellOut + (size_t)browg * 1024 + cs * 16 + jp) = make_float2(cf0, cf1);
}

// ---------- launcher ----------
extern "C" void kernel_launch(void* const* d_in, const int* in_sizes, int n_in,
                              void* d_out, int out_size, void* d_ws, size_t ws_size,
                              hipStream_t stream) {
  const float* x   = (const float*)d_in[0];
  const float* Wf  = (const float*)d_in[1];
  const float* bfv = (const float*)d_in[2];
  const float* Wi1 = (const float*)d_in[3];
  const float* bi1 = (const float*)d_in[4];
  const float* Wi2 = (const float*)d_in[5];
  const float* bi2 = (const float*)d_in[6];
  const float* Wo  = (const float*)d_in[7];
  const float* bo  = (const float*)d_in[8];
  const float* Wc  = (const float*)d_in[9];
  const float* bc  = (const float*)d_in[10];
  float* out = (float*)d_out;

  if (ws_size < WS_NEEDED) return;  // visible failure instead of corruption

  char* ws = (char*)d_ws;
  unsigned short* xb      = (unsigned short*)(ws + OFF_XB);
  unsigned short* WhT     = (unsigned short*)(ws + OFF_WHT);
  unsigned short* WxT     = (unsigned short*)(ws + OFF_WXT);
  unsigned short* WcT     = (unsigned short*)(ws + OFF_WCT);
  float*          biasAll = (float*)(ws + OFF_BIAS);
  unsigned short* XW      = (unsigned short*)(ws + OFF_XW);
  unsigned short* H       = (unsigned short*)(ws + OFF_H);
  unsigned short* cB0     = (unsigned short*)(ws + OFF_CB);
  unsigned short* cB1     = (unsigned short*)(ws + OFF_CB + (size_t)128 * 1024 * 2);
  unsigned*       barLn   = (unsigned*)(ws + OFF_BAR);
  float*          cellOut = out + (size_t)32768 * 1024;

  hipMemsetAsync(cB0, 0, (size_t)128 * 1024 * 2, stream);
  hipMemsetAsync(barLn, 0, 16384, stream);    // reset barrier lines EVERY launch

  cvt_x_kernel <<<32768, 256, 0, stream>>>(x, xb);
  cvt_w_kernel <<< 1024, 256, 0, stream>>>(Wf, Wi1, Wi2, Wo, WhT, WxT);
  bias_kernel  <<<   16, 256, 0, stream>>>(bfv, bi1, bi2, bo, biasAll);
  cvt_wc_kernel<<< 4096, 256, 0, stream>>>(Wc, WcT);

  // XW = x @ Wx_all + biases   (M=32768, N=4096, K=1024), bf16 out, 256^2 tiles
  gemm_bt<false><<<dim3(16, 128), 512, 0, stream>>>(xb, WxT, biasAll, XW, 32768, 4096, 1024);

  // persistent recurrence: 256 WGs x 512 threads (r7-proven), cooperative
  {
    void* args[] = { (void*)&WhT, (void*)&XW, (void*)&H,
                     (void*)&cB0, (void*)&cB1, (void*)&cellOut, (void*)&barLn };
    hipLaunchCooperativeKernel(lstm_persist, dim3(256), dim3(512), args, 0u, stream);
  }

  // output_sequence = h @ Wc + bc  (M=32768, N=1024, K=1024), f32 out
  gemm_bt<true><<<dim3(4, 128), 512, 0, stream>>>(H, WcT, bc, out, 32768, 1024, 1024);
}

// Round 13
// 1414.922 us; speedup vs baseline: 1.4664x; 1.0606x over previous
//
#include <hip/hip_runtime.h>
#include <cstdint>
#include <cstddef>

#define DEVINL __device__ __forceinline__

typedef __attribute__((ext_vector_type(8))) short bf16x8;
typedef __attribute__((ext_vector_type(4))) float f32x4;
typedef __attribute__((ext_vector_type(4))) unsigned short u16x4;
typedef __attribute__((ext_vector_type(4))) unsigned int u32x4;

// ---------- workspace layout ----------
static constexpr size_t OFF_XB   = 0;                              // x bf16 [32768][1024]
static constexpr size_t OFF_WHT  = OFF_XB  + (size_t)32768*1024*2; // Wh^T bf16 [4096][1024]
static constexpr size_t OFF_WXT  = OFF_WHT + (size_t)4096*1024*2;  // Wx^T bf16 [4096][1024]
static constexpr size_t OFF_WCT  = OFF_WXT + (size_t)4096*1024*2;  // Wc^T bf16 [1024][1024]
static constexpr size_t OFF_BIAS = OFF_WCT + (size_t)1024*1024*2;  // bias_all f32 [4096]
static constexpr size_t OFF_XW   = OFF_BIAS + 4096*4;              // XW bf16 [32768][4096]
static constexpr size_t OFF_H    = OFF_XW  + (size_t)32768*4096*2; // h bf16 [32768][1024]
static constexpr size_t OFF_CB   = OFF_H   + (size_t)32768*1024*2; // cell bf16 x2 [128][1024]
static constexpr size_t OFF_BAR  = OFF_CB  + (size_t)2*128*1024*2; // barrier lines, 32 KB
static constexpr size_t WS_NEEDED = OFF_BAR + 32768;

// ---------- helpers ----------
DEVINL unsigned short f2b(float f) {
  union { float f; unsigned u; } v; v.f = f;
  unsigned r = (v.u + 0x7FFFu + ((v.u >> 16) & 1u)) >> 16;  // RNE
  return (unsigned short)r;
}
DEVINL float b2f(unsigned short h) {
  union { unsigned u; float f; } v; v.u = ((unsigned)h) << 16;
  return v.f;
}
DEVINL float sigmoidf_(float x) { return 1.0f / (1.0f + __expf(-x)); }
DEVINL float tanhf_(float x) { float e = __expf(2.0f * x); return 1.0f - 2.0f / (e + 1.0f); }
DEVINL f32x4 MFMA(bf16x8 a, bf16x8 b, f32x4 c) {
  return __builtin_amdgcn_mfma_f32_16x16x32_bf16(a, b, c, 0, 0, 0);
}
DEVINL void gload16(const void* g, void* l) {
  __builtin_amdgcn_global_load_lds(
      (const __attribute__((address_space(1))) void*)g,
      (__attribute__((address_space(3))) void*)l, 16, 0, 0);
}

// ---------- conversions ----------
__global__ void cvt_x_kernel(const float* __restrict__ x, unsigned short* __restrict__ xb) {
  size_t i = ((size_t)blockIdx.x * 256 + threadIdx.x) * 4;
  float4 v = *(const float4*)(x + i);
  u16x4 o; o.x = f2b(v.x); o.y = f2b(v.y); o.z = f2b(v.z); o.w = f2b(v.w);
  *(u16x4*)(xb + i) = o;
}

// coalesced transpose-convert via 64x64 LDS tile (proven r8)
__global__ __launch_bounds__(256)
void cvt_w_kernel(const float* __restrict__ Wf, const float* __restrict__ Wi1,
                  const float* __restrict__ Wi2, const float* __restrict__ Wo,
                  unsigned short* __restrict__ WhT, unsigned short* __restrict__ WxT) {
  __shared__ float tile[64][65];
  const int bid = blockIdx.x;          // 16 jt x 16 kt x 4 g = 1024 blocks
  const int g  = bid & 3;
  const int kt = (bid >> 2) & 15;
  const int jt = bid >> 6;
  const float* W = (g == 0) ? Wf : (g == 1) ? Wi1 : (g == 2) ? Wi2 : Wo;
  const int tid = threadIdx.x;
  const int jj  = tid & 63;
  const int kr  = tid >> 6;            // 0..3

  for (int h = 0; h < 2; ++h) {
    const float* Wb = W + (size_t)(h ? 1024 : 0) * 1024;
#pragma unroll
    for (int i = 0; i < 16; ++i) {
      int kl = i * 4 + kr;
      tile[kl][jj] = Wb[(size_t)(kt * 64 + kl) * 1024 + jt * 64 + jj];
    }
    __syncthreads();
    unsigned short* Out = h ? WxT : WhT;
    unsigned short* op  = Out + (size_t)(4 * (jt * 64 + jj) + g) * 1024 + kt * 64 + kr * 16;
#pragma unroll
    for (int q = 0; q < 4; ++q) {
      u16x4 v;
#pragma unroll
      for (int e = 0; e < 4; ++e)
        ((unsigned short*)&v)[e] = f2b(tile[kr * 16 + q * 4 + e][jj]);
      *(u16x4*)(op + q * 4) = v;
    }
    __syncthreads();
  }
}

__global__ void bias_kernel(const float* __restrict__ bf_, const float* __restrict__ bi1,
                            const float* __restrict__ bi2, const float* __restrict__ bo,
                            float* __restrict__ biasAll) {
  int gc = blockIdx.x * 256 + threadIdx.x;   // 4096
  int j = gc >> 2, g = gc & 3;
  const float* bb = (g == 0) ? bf_ : (g == 1) ? bi1 : (g == 2) ? bi2 : bo;
  biasAll[gc] = bb[j];
}

__global__ void cvt_wc_kernel(const float* __restrict__ Wc, unsigned short* __restrict__ WcT) {
  int idx = blockIdx.x * 256 + threadIdx.x;   // 1024*1024 total
  int k = idx & 1023, n = idx >> 10;
  WcT[idx] = f2b(Wc[(size_t)k * 1024 + n]);
}

// ---------- 256x256 pipelined bf16 GEMM (r12-proven) ----------
template<bool OUT_F32>
__global__ __launch_bounds__(512, 2)
void gemm_bt(const unsigned short* __restrict__ A,
             const unsigned short* __restrict__ Bt,
             const float* __restrict__ bias,
             void* __restrict__ C,
             int M, int N, int K) {
  __shared__ char sT[4][32768];        // per buf: A[256][32] @0, B[256][32] @16384
  const int tid  = threadIdx.x;
  const int lane = tid & 63;
  const int wid  = tid >> 6;
  const int wm   = (wid >> 2) * 128;
  const int wn   = (wid & 3) * 64;

  const int nwg = gridDim.x * gridDim.y;
  const int lin = blockIdx.y * gridDim.x + blockIdx.x;
  const int cpx = nwg >> 3;
  const int swz = (lin & 7) * cpx + (lin >> 3);
  const int m0  = (swz / gridDim.x) * 256;
  const int n0  = (swz % gridDim.x) * 256;

  const int nt = K >> 5;

  f32x4 acc[8][4];
#pragma unroll
  for (int i = 0; i < 8; ++i)
#pragma unroll
    for (int j = 0; j < 4; ++j) acc[i][j] = (f32x4){0.f, 0.f, 0.f, 0.f};

  auto stageA = [&](int kt, int buf) {
#pragma unroll
    for (int l = 0; l < 2; ++l) {
      int s = l * 512 + tid;
      int r = s >> 2, c = s & 3;
      int cg = c ^ ((r >> 1) & 3);
      gload16(A + (size_t)(m0 + r) * K + kt * 32 + cg * 8, sT[buf] + s * 16);
    }
  };
  auto stageB = [&](int kt, int buf) {
#pragma unroll
    for (int l = 0; l < 2; ++l) {
      int s = l * 512 + tid;
      int r = s >> 2, c = s & 3;
      int cg = c ^ ((r >> 1) & 3);
      gload16(Bt + (size_t)(n0 + r) * K + kt * 32 + cg * 8, sT[buf] + 16384 + s * 16);
    }
  };

  stageA(0, 0); stageB(0, 0);
  stageA(1, 1); stageB(1, 1);
  stageA(2, 2); stageB(2, 2);
  asm volatile("s_waitcnt vmcnt(8)" ::: "memory");
  __builtin_amdgcn_s_barrier();

  const int ch = lane >> 4;

#pragma unroll 1
  for (int g = 0; g < nt; ++g) {
    const int rb = g & 3;
    const char* ab = sT[rb];
    const char* bb = sT[rb] + 16384;

    bf16x8 bv[4], av[4];
#pragma unroll
    for (int ni = 0; ni < 4; ++ni) {
      int col = wn + ni * 16 + (lane & 15);
      bv[ni] = *(const bf16x8*)(bb + col * 64 + ((ch ^ ((col >> 1) & 3)) << 4));
    }
#pragma unroll
    for (int mi = 0; mi < 4; ++mi) {
      int row = wm + mi * 16 + (lane & 15);
      av[mi] = *(const bf16x8*)(ab + row * 64 + ((ch ^ ((row >> 1) & 3)) << 4));
    }
    if (g + 3 < nt) stageA(g + 3, (g + 3) & 3);
    __builtin_amdgcn_s_barrier();
    __builtin_amdgcn_s_setprio(1);
#pragma unroll
    for (int mi = 0; mi < 4; ++mi)
#pragma unroll
      for (int ni = 0; ni < 4; ++ni)
        acc[mi][ni] = MFMA(av[mi], bv[ni], acc[mi][ni]);
    __builtin_amdgcn_s_setprio(0);
    __builtin_amdgcn_s_barrier();

#pragma unroll
    for (int mi = 0; mi < 4; ++mi) {
      int row = wm + 64 + mi * 16 + (lane & 15);
      av[mi] = *(const bf16x8*)(ab + row * 64 + ((ch ^ ((row >> 1) & 3)) << 4));
    }
    if (g + 3 < nt) stageB(g + 3, (g + 3) & 3);
    __builtin_amdgcn_s_barrier();
    __builtin_amdgcn_s_setprio(1);
#pragma unroll
    for (int mi = 0; mi < 4; ++mi)
#pragma unroll
      for (int ni = 0; ni < 4; ++ni)
        acc[mi + 4][ni] = MFMA(av[mi], bv[ni], acc[mi + 4][ni]);
    __builtin_amdgcn_s_setprio(0);

    if (g <= nt - 4)      asm volatile("s_waitcnt vmcnt(8)" ::: "memory");
    else if (g == nt - 3) asm volatile("s_waitcnt vmcnt(4)" ::: "memory");
    else if (g == nt - 2) asm volatile("s_waitcnt vmcnt(0)" ::: "memory");
    __builtin_amdgcn_s_barrier();
  }

#pragma unroll
  for (int mi = 0; mi < 8; ++mi)
#pragma unroll
    for (int ni = 0; ni < 4; ++ni)
#pragma unroll
      for (int r = 0; r < 4; ++r) {
        int row = m0 + wm + mi * 16 + (lane >> 4) * 4 + r;
        int col = n0 + wn + ni * 16 + (lane & 15);
        float v = acc[mi][ni][r] + bias[col];
        if (OUT_F32) ((float*)C)[(size_t)row * N + col] = v;
        else ((unsigned short*)C)[(size_t)row * N + col] = f2b(v);
      }
}

// ---------- persistent recurrence v13: 8 row-groups of 16 rows ----------
// 256 WGs x 512 threads (proven coop envelope). WG (mq, cs): mq = wgid&7 ->
// batch rows 16mq..+16 (8 INDEPENDENT row-groups); cs = wgid>>3 (0..31) ->
// gate-cols 128cs..+128 (= cell cols 32cs..+32). Wave nh (0..7): one 16x16
// MFMA tile, gate-cols 128cs+16nh..+16, 32 MFMA/step. vs r7: per-WG A-tile
// halves (32KB), MALL broadcast 16->8 MB/step, staging 8->4 loads/thread,
// barrier participants 64->32 (lvl1 subgroups of 4). MALL protocol byte-
// identical to r5/r7/r12: cell stores = relaxed agent atomics; cell loads =
// sc0|sc1 asm; H plain cached; tree barrier, tid0 only, no fences.
__global__ __launch_bounds__(512, 2)
void lstm_persist(const unsigned short* __restrict__ WhT,  // [4096][1024] bf16
                  const unsigned short* __restrict__ XW,   // [32768][4096] bf16
                  unsigned short* __restrict__ H,          // [32768][1024] bf16
                  unsigned short* __restrict__ cB0,        // [128][1024] bf16
                  unsigned short* __restrict__ cB1,
                  float* __restrict__ cellOut,             // [128][1024] f32
                  unsigned* __restrict__ bar) {
  __shared__ __align__(16) char  sA[16 * 2064];   // 33 KB A-tile, padded stride
  __shared__ __align__(16) float sP[16 * 132];    // 8.4 KB preact redistribute

  const int tid  = threadIdx.x;
  const int lane = tid & 63;
  const int nh   = tid >> 6;       // wave id = n-tile 0..7
  const int wgid = blockIdx.x;
  const int mq   = wgid & 7;       // row-group (16 rows)
  const int cs   = wgid >> 3;      // col slice 0..31 (128 gate-cols)
  const int sg   = cs >> 2;        // subgroup 0..7 (4 WGs each)

  // barrier lines (256B spacing): qc 0..511, qf 512..1023, gcnt 1024..5119
  unsigned* qc   = bar + mq * 64;
  unsigned* qf   = bar + 512 + mq * 64;
  unsigned* gcnt = bar + 1024 + (mq * 8 + sg) * 64;

  const int r0 = lane & 15;        // row within m-tile / col within n-tile
  const int ch = lane >> 4;        // 16B chunk id within K-slice

  // ---- Wh fragments in registers: volatile loads (non-remat), 128 regs ----
  bf16x8 bfr[32];
  {
    const unsigned short* bp = WhT + (size_t)(cs * 128 + nh * 16 + r0) * 1024 + ch * 8;
#pragma unroll
    for (int ks = 0; ks < 32; ++ks)
      bfr[ks] = *(const volatile bf16x8*)(bp + ks * 32);
  }

  // ---- per-thread cell ownership (threads 0..255): 2 cell cols, same row ----
  const int b_local = (tid & 255) >> 4;  // 0..15
  const int jp      = (tid & 15) * 2;    // 0,2,..,30
  const int browg   = mq * 16 + b_local; // global batch row
  float cf0 = 0.f, cf1 = 0.f;

  const unsigned short* xwp = XW + (size_t)browg * 256 * 4096 + cs * 128 + jp * 4;
  unsigned* c0p = (unsigned*)(cB0 + (size_t)browg * 1024 + cs * 32 + jp);
  unsigned* c1p = (unsigned*)(cB1 + (size_t)browg * 1024 + cs * 32 + jp);
  unsigned short* hp = H + (size_t)browg * 256 * 1024 + cs * 32 + jp;

  // staging geometry: thread covers rows {4it+strow}, 16B chunk stcc
  const int strow = tid >> 7;            // 0..3
  const int stcc  = tid & 127;           // 0..127

  for (int t = 0; t < 256; ++t) {
    const unsigned short* cinq = ((t & 1) ? cB1 : cB0) + (size_t)mq * 16 * 1024;

    // x-contribution (8 gate preacts, 16B) — plain cached, tid<256
    bf16x8 xw;
    if (tid < 256) xw = *(const bf16x8*)(xwp + (size_t)t * 4096);

    // ---- stage A-tile [16][1024] bf16: coherent loads -> regs -> LDS ----
    u32x4 st[4];
#pragma unroll
    for (int it = 0; it < 4; ++it) {
      const void* p = cinq + (size_t)(it * 4 + strow) * 1024 + stcc * 8;
      asm volatile("global_load_dwordx4 %0, %1, off sc0 sc1"
                   : "=&v"(st[it]) : "v"(p) : "memory");
    }
    asm volatile("s_waitcnt vmcnt(0)" ::: "memory");
    __builtin_amdgcn_sched_barrier(0);
#pragma unroll
    for (int it = 0; it < 4; ++it) {
      int r = it * 4 + strow;
      *(u32x4*)&sA[r * 2064 + stcc * 16] = st[it];
    }
    __syncthreads();   // sA ready

    // ---- GEMM: one 16x16 tile per wave, K=1024; A LDS, B regs ----
    f32x4 acc = (f32x4){0.f, 0.f, 0.f, 0.f};
#pragma unroll
    for (int ks = 0; ks < 32; ++ks) {
      bf16x8 a0 = *(const bf16x8*)&sA[r0 * 2064 + (ch + ks * 4) * 16];
      acc = MFMA(a0, bfr[ks], acc);
    }

    // ---- redistribute preacts via LDS ----
#pragma unroll
    for (int rr = 0; rr < 4; ++rr)
      sP[(ch * 4 + rr) * 132 + nh * 16 + r0] = acc[rr];
    __syncthreads();   // sP ready

    if (tid < 256) {
      float4 g0 = *(const float4*)&sP[b_local * 132 + jp * 4];
      float4 g1 = *(const float4*)&sP[b_local * 132 + jp * 4 + 4];

      // ---- elementwise for 2 cells ----
      float c2a, c2b, ha, hb;
      {
        float pf = g0.x + b2f((unsigned short)xw[0]);
        float pi = g0.y + b2f((unsigned short)xw[1]);
        float pg = g0.z + b2f((unsigned short)xw[2]);
        float po = g0.w + b2f((unsigned short)xw[3]);
        float f = sigmoidf_(pf), i1 = sigmoidf_(pi), gg = tanhf_(pg), o = sigmoidf_(po);
        c2a = cf0 * f + i1 * gg; cf0 = c2a; ha = o * tanhf_(c2a);
      }
      {
        float pf = g1.x + b2f((unsigned short)xw[4]);
        float pi = g1.y + b2f((unsigned short)xw[5]);
        float pg = g1.z + b2f((unsigned short)xw[6]);
        float po = g1.w + b2f((unsigned short)xw[7]);
        float f = sigmoidf_(pf), i1 = sigmoidf_(pi), gg = tanhf_(pg), o = sigmoidf_(po);
        c2b = cf1 * f + i1 * gg; cf1 = c2b; hb = o * tanhf_(c2b);
      }

      // cell: agent-scope atomic store (write-through to MALL, chip-coherent)
      unsigned cw = (unsigned)f2b(c2a) | ((unsigned)f2b(c2b) << 16);
      __hip_atomic_store((t & 1) ? c0p : c1p, cw,
                         __ATOMIC_RELAXED, __HIP_MEMORY_SCOPE_AGENT);
      // h: plain cached store (consumed after kernel end)
      unsigned hw = (unsigned)f2b(ha) | ((unsigned)f2b(hb) << 16);
      *(unsigned*)(hp + (size_t)t * 1024) = hw;
    }

    // ---- per-row-group 2-level tree barrier (8 subgroups x 4 WGs) ----
    __syncthreads();   // vmcnt drain: cell stores at MALL
    if (tid == 0) {
      unsigned tgt1 = 4u * (unsigned)(t + 1);   // subgroup count
      unsigned tgt2 = 8u * (unsigned)(t + 1);   // subgroups completed
      unsigned n = __hip_atomic_fetch_add(gcnt, 1u, __ATOMIC_RELAXED,
                                          __HIP_MEMORY_SCOPE_AGENT);
      if (n == tgt1 - 1u) {          // last of the 4-WG subgroup
        unsigned m = __hip_atomic_fetch_add(qc, 1u, __ATOMIC_RELAXED,
                                            __HIP_MEMORY_SCOPE_AGENT);
        if (m == tgt2 - 1u)          // last of the 8 subgroups
          __hip_atomic_store(qf, (unsigned)(t + 1),
                             __ATOMIC_RELAXED, __HIP_MEMORY_SCOPE_AGENT);
      }
      while (__hip_atomic_load(qf, __ATOMIC_RELAXED, __HIP_MEMORY_SCOPE_AGENT)
             < (unsigned)(t + 1))
        __builtin_amdgcn_s_sleep(1);
    }
    __syncthreads();
  }

  // final f32 cell state from registers (kernel-end flush covers it)
  if (tid < 256)
    *(float2*)(cellOut + (size_t)browg * 1024 + cs * 32 + jp) = make_float2(cf0, cf1);
}

// ---------- launcher ----------
extern "C" void kernel_launch(void* const* d_in, const int* in_sizes, int n_in,
                              void* d_out, int out_size, void* d_ws, size_t ws_size,
                              hipStream_t stream) {
  const float* x   = (const float*)d_in[0];
  const float* Wf  = (const float*)d_in[1];
  const float* bfv = (const float*)d_in[2];
  const float* Wi1 = (const float*)d_in[3];
  const float* bi1 = (const float*)d_in[4];
  const float* Wi2 = (const float*)d_in[5];
  const float* bi2 = (const float*)d_in[6];
  const float* Wo  = (const float*)d_in[7];
  const float* bo  = (const float*)d_in[8];
  const float* Wc  = (const float*)d_in[9];
  const float* bc  = (const float*)d_in[10];
  float* out = (float*)d_out;

  if (ws_size < WS_NEEDED) return;  // visible failure instead of corruption

  char* ws = (char*)d_ws;
  unsigned short* xb      = (unsigned short*)(ws + OFF_XB);
  unsigned short* WhT     = (unsigned short*)(ws + OFF_WHT);
  unsigned short* WxT     = (unsigned short*)(ws + OFF_WXT);
  unsigned short* WcT     = (unsigned short*)(ws + OFF_WCT);
  float*          biasAll = (float*)(ws + OFF_BIAS);
  unsigned short* XW      = (unsigned short*)(ws + OFF_XW);
  unsigned short* H       = (unsigned short*)(ws + OFF_H);
  unsigned short* cB0     = (unsigned short*)(ws + OFF_CB);
  unsigned short* cB1     = (unsigned short*)(ws + OFF_CB + (size_t)128 * 1024 * 2);
  unsigned*       barLn   = (unsigned*)(ws + OFF_BAR);
  float*          cellOut = out + (size_t)32768 * 1024;

  hipMemsetAsync(cB0, 0, (size_t)128 * 1024 * 2, stream);
  hipMemsetAsync(barLn, 0, 32768, stream);    // reset barrier lines EVERY launch

  cvt_x_kernel <<<32768, 256, 0, stream>>>(x, xb);
  cvt_w_kernel <<< 1024, 256, 0, stream>>>(Wf, Wi1, Wi2, Wo, WhT, WxT);
  bias_kernel  <<<   16, 256, 0, stream>>>(bfv, bi1, bi2, bo, biasAll);
  cvt_wc_kernel<<< 4096, 256, 0, stream>>>(Wc, WcT);

  // XW = x @ Wx_all + biases   (M=32768, N=4096, K=1024), bf16 out, 256^2 tiles
  gemm_bt<false><<<dim3(16, 128), 512, 0, stream>>>(xb, WxT, biasAll, XW, 32768, 4096, 1024);

  // persistent recurrence: 256 WGs x 512 threads (proven envelope), cooperative
  {
    void* args[] = { (void*)&WhT, (void*)&XW, (void*)&H,
                     (void*)&cB0, (void*)&cB1, (void*)&cellOut, (void*)&barLn };
    hipLaunchCooperativeKernel(lstm_persist, dim3(256), dim3(512), args, 0u, stream);
  }

  // output_sequence = h @ Wc + bc  (M=32768, N=1024, K=1024), f32 out
  gemm_bt<true><<<dim3(4, 128), 512, 0, stream>>>(H, WcT, bc, out, 32768, 1024, 1024);
}

// Round 14
// 1337.998 us; speedup vs baseline: 1.5507x; 1.0575x over previous
//
#include <hip/hip_runtime.h>
#include <cstdint>
#include <cstddef>

#define DEVINL __device__ __forceinline__

typedef __attribute__((ext_vector_type(8))) short bf16x8;
typedef __attribute__((ext_vector_type(4))) float f32x4;
typedef __attribute__((ext_vector_type(4))) unsigned short u16x4;
typedef __attribute__((ext_vector_type(4))) unsigned int u32x4;

// ---------- workspace layout ----------
static constexpr size_t OFF_XB   = 0;                              // x bf16 [32768][1024]
static constexpr size_t OFF_WHT  = OFF_XB  + (size_t)32768*1024*2; // Wh^T bf16 [4096][1024]
static constexpr size_t OFF_WXT  = OFF_WHT + (size_t)4096*1024*2;  // Wx^T bf16 [4096][1024]
static constexpr size_t OFF_WCT  = OFF_WXT + (size_t)4096*1024*2;  // Wc^T bf16 [1024][1024]
static constexpr size_t OFF_BIAS = OFF_WCT + (size_t)1024*1024*2;  // bias_all f32 [4096]
static constexpr size_t OFF_XW   = OFF_BIAS + 4096*4;              // XW bf16 [32768][4096]
static constexpr size_t OFF_H    = OFF_XW  + (size_t)32768*4096*2; // h bf16 [32768][1024]
static constexpr size_t OFF_CB   = OFF_H   + (size_t)32768*1024*2; // cell bf16 x2 [128][1024]
static constexpr size_t OFF_BAR  = OFF_CB  + (size_t)2*128*1024*2; // barrier lines, 32 KB
static constexpr size_t WS_NEEDED = OFF_BAR + 32768;

// ---------- helpers ----------
DEVINL unsigned short f2b(float f) {
  union { float f; unsigned u; } v; v.f = f;
  unsigned r = (v.u + 0x7FFFu + ((v.u >> 16) & 1u)) >> 16;  // RNE
  return (unsigned short)r;
}
DEVINL float b2f(unsigned short h) {
  union { unsigned u; float f; } v; v.u = ((unsigned)h) << 16;
  return v.f;
}
DEVINL float sigmoidf_(float x) { return 1.0f / (1.0f + __expf(-x)); }
DEVINL float tanhf_(float x) { float e = __expf(2.0f * x); return 1.0f - 2.0f / (e + 1.0f); }
DEVINL f32x4 MFMA(bf16x8 a, bf16x8 b, f32x4 c) {
  return __builtin_amdgcn_mfma_f32_16x16x32_bf16(a, b, c, 0, 0, 0);
}
DEVINL void gload16(const void* g, void* l) {
  __builtin_amdgcn_global_load_lds(
      (const __attribute__((address_space(1))) void*)g,
      (__attribute__((address_space(3))) void*)l, 16, 0, 0);
}

// ---------- conversions ----------
__global__ void cvt_x_kernel(const float* __restrict__ x, unsigned short* __restrict__ xb) {
  size_t i = ((size_t)blockIdx.x * 256 + threadIdx.x) * 4;
  float4 v = *(const float4*)(x + i);
  u16x4 o; o.x = f2b(v.x); o.y = f2b(v.y); o.z = f2b(v.z); o.w = f2b(v.w);
  *(u16x4*)(xb + i) = o;
}

// coalesced transpose-convert via 64x64 LDS tile (proven r8)
__global__ __launch_bounds__(256)
void cvt_w_kernel(const float* __restrict__ Wf, const float* __restrict__ Wi1,
                  const float* __restrict__ Wi2, const float* __restrict__ Wo,
                  unsigned short* __restrict__ WhT, unsigned short* __restrict__ WxT) {
  __shared__ float tile[64][65];
  const int bid = blockIdx.x;          // 16 jt x 16 kt x 4 g = 1024 blocks
  const int g  = bid & 3;
  const int kt = (bid >> 2) & 15;
  const int jt = bid >> 6;
  const float* W = (g == 0) ? Wf : (g == 1) ? Wi1 : (g == 2) ? Wi2 : Wo;
  const int tid = threadIdx.x;
  const int jj  = tid & 63;
  const int kr  = tid >> 6;            // 0..3

  for (int h = 0; h < 2; ++h) {
    const float* Wb = W + (size_t)(h ? 1024 : 0) * 1024;
#pragma unroll
    for (int i = 0; i < 16; ++i) {
      int kl = i * 4 + kr;
      tile[kl][jj] = Wb[(size_t)(kt * 64 + kl) * 1024 + jt * 64 + jj];
    }
    __syncthreads();
    unsigned short* Out = h ? WxT : WhT;
    unsigned short* op  = Out + (size_t)(4 * (jt * 64 + jj) + g) * 1024 + kt * 64 + kr * 16;
#pragma unroll
    for (int q = 0; q < 4; ++q) {
      u16x4 v;
#pragma unroll
      for (int e = 0; e < 4; ++e)
        ((unsigned short*)&v)[e] = f2b(tile[kr * 16 + q * 4 + e][jj]);
      *(u16x4*)(op + q * 4) = v;
    }
    __syncthreads();
  }
}

__global__ void bias_kernel(const float* __restrict__ bf_, const float* __restrict__ bi1,
                            const float* __restrict__ bi2, const float* __restrict__ bo,
                            float* __restrict__ biasAll) {
  int gc = blockIdx.x * 256 + threadIdx.x;   // 4096
  int j = gc >> 2, g = gc & 3;
  const float* bb = (g == 0) ? bf_ : (g == 1) ? bi1 : (g == 2) ? bi2 : bo;
  biasAll[gc] = bb[j];
}

__global__ void cvt_wc_kernel(const float* __restrict__ Wc, unsigned short* __restrict__ WcT) {
  int idx = blockIdx.x * 256 + threadIdx.x;   // 1024*1024 total
  int k = idx & 1023, n = idx >> 10;
  WcT[idx] = f2b(Wc[(size_t)k * 1024 + n]);
}

// ---------- 256x256 pipelined bf16 GEMM (r12-proven) ----------
template<bool OUT_F32>
__global__ __launch_bounds__(512, 2)
void gemm_bt(const unsigned short* __restrict__ A,
             const unsigned short* __restrict__ Bt,
             const float* __restrict__ bias,
             void* __restrict__ C,
             int M, int N, int K) {
  __shared__ char sT[4][32768];        // per buf: A[256][32] @0, B[256][32] @16384
  const int tid  = threadIdx.x;
  const int lane = tid & 63;
  const int wid  = tid >> 6;
  const int wm   = (wid >> 2) * 128;
  const int wn   = (wid & 3) * 64;

  const int nwg = gridDim.x * gridDim.y;
  const int lin = blockIdx.y * gridDim.x + blockIdx.x;
  const int cpx = nwg >> 3;
  const int swz = (lin & 7) * cpx + (lin >> 3);
  const int m0  = (swz / gridDim.x) * 256;
  const int n0  = (swz % gridDim.x) * 256;

  const int nt = K >> 5;

  f32x4 acc[8][4];
#pragma unroll
  for (int i = 0; i < 8; ++i)
#pragma unroll
    for (int j = 0; j < 4; ++j) acc[i][j] = (f32x4){0.f, 0.f, 0.f, 0.f};

  auto stageA = [&](int kt, int buf) {
#pragma unroll
    for (int l = 0; l < 2; ++l) {
      int s = l * 512 + tid;
      int r = s >> 2, c = s & 3;
      int cg = c ^ ((r >> 1) & 3);
      gload16(A + (size_t)(m0 + r) * K + kt * 32 + cg * 8, sT[buf] + s * 16);
    }
  };
  auto stageB = [&](int kt, int buf) {
#pragma unroll
    for (int l = 0; l < 2; ++l) {
      int s = l * 512 + tid;
      int r = s >> 2, c = s & 3;
      int cg = c ^ ((r >> 1) & 3);
      gload16(Bt + (size_t)(n0 + r) * K + kt * 32 + cg * 8, sT[buf] + 16384 + s * 16);
    }
  };

  stageA(0, 0); stageB(0, 0);
  stageA(1, 1); stageB(1, 1);
  stageA(2, 2); stageB(2, 2);
  asm volatile("s_waitcnt vmcnt(8)" ::: "memory");
  __builtin_amdgcn_s_barrier();

  const int ch = lane >> 4;

#pragma unroll 1
  for (int g = 0; g < nt; ++g) {
    const int rb = g & 3;
    const char* ab = sT[rb];
    const char* bb = sT[rb] + 16384;

    bf16x8 bv[4], av[4];
#pragma unroll
    for (int ni = 0; ni < 4; ++ni) {
      int col = wn + ni * 16 + (lane & 15);
      bv[ni] = *(const bf16x8*)(bb + col * 64 + ((ch ^ ((col >> 1) & 3)) << 4));
    }
#pragma unroll
    for (int mi = 0; mi < 4; ++mi) {
      int row = wm + mi * 16 + (lane & 15);
      av[mi] = *(const bf16x8*)(ab + row * 64 + ((ch ^ ((row >> 1) & 3)) << 4));
    }
    if (g + 3 < nt) stageA(g + 3, (g + 3) & 3);
    __builtin_amdgcn_s_barrier();
    __builtin_amdgcn_s_setprio(1);
#pragma unroll
    for (int mi = 0; mi < 4; ++mi)
#pragma unroll
      for (int ni = 0; ni < 4; ++ni)
        acc[mi][ni] = MFMA(av[mi], bv[ni], acc[mi][ni]);
    __builtin_amdgcn_s_setprio(0);
    __builtin_amdgcn_s_barrier();

#pragma unroll
    for (int mi = 0; mi < 4; ++mi) {
      int row = wm + 64 + mi * 16 + (lane & 15);
      av[mi] = *(const bf16x8*)(ab + row * 64 + ((ch ^ ((row >> 1) & 3)) << 4));
    }
    if (g + 3 < nt) stageB(g + 3, (g + 3) & 3);
    __builtin_amdgcn_s_barrier();
    __builtin_amdgcn_s_setprio(1);
#pragma unroll
    for (int mi = 0; mi < 4; ++mi)
#pragma unroll
      for (int ni = 0; ni < 4; ++ni)
        acc[mi + 4][ni] = MFMA(av[mi], bv[ni], acc[mi + 4][ni]);
    __builtin_amdgcn_s_setprio(0);

    if (g <= nt - 4)      asm volatile("s_waitcnt vmcnt(8)" ::: "memory");
    else if (g == nt - 3) asm volatile("s_waitcnt vmcnt(4)" ::: "memory");
    else if (g == nt - 2) asm volatile("s_waitcnt vmcnt(0)" ::: "memory");
    __builtin_amdgcn_s_barrier();
  }

#pragma unroll
  for (int mi = 0; mi < 8; ++mi)
#pragma unroll
    for (int ni = 0; ni < 4; ++ni)
#pragma unroll
      for (int r = 0; r < 4; ++r) {
        int row = m0 + wm + mi * 16 + (lane >> 4) * 4 + r;
        int col = n0 + wn + ni * 16 + (lane & 15);
        float v = acc[mi][ni][r] + bias[col];
        if (OUT_F32) ((float*)C)[(size_t)row * N + col] = v;
        else ((unsigned short*)C)[(size_t)row * N + col] = f2b(v);
      }
}

// ---------- persistent recurrence v14: r13 + spin-window fill ----------
// Identical envelope/protocol/decomposition to r13 (1005us): 256 WGs x 512
// thr, 8 row-groups x 32 WGs, MALL protocol, 2-level tree barrier.
// Changes (latency scheduling only, same arithmetic):
//  (1) elementwise spread over ALL 512 threads (1 cell each, 3 exp on the
//      critical path instead of 6); cell/H stores packed to u32 via
//      intra-wave __shfl_down (adjacent lanes = adjacent cols).
//  (2) h computation + H store DEFERRED past the signal -> runs in the
//      spin window (o, tanh(c2), pack, store off the critical path).
//  (3) next step's XW row prefetched in the spin window.
__global__ __launch_bounds__(512, 2)
void lstm_persist(const unsigned short* __restrict__ WhT,  // [4096][1024] bf16
                  const unsigned short* __restrict__ XW,   // [32768][4096] bf16
                  unsigned short* __restrict__ H,          // [32768][1024] bf16
                  unsigned short* __restrict__ cB0,        // [128][1024] bf16
                  unsigned short* __restrict__ cB1,
                  float* __restrict__ cellOut,             // [128][1024] f32
                  unsigned* __restrict__ bar) {
  __shared__ __align__(16) char  sA[16 * 2064];   // 33 KB A-tile, padded stride
  __shared__ __align__(16) float sP[16 * 132];    // 8.4 KB preact redistribute

  const int tid  = threadIdx.x;
  const int lane = tid & 63;
  const int nh   = tid >> 6;       // wave id = n-tile 0..7
  const int wgid = blockIdx.x;
  const int mq   = wgid & 7;       // row-group (16 rows)
  const int cs   = wgid >> 3;      // col slice 0..31 (128 gate-cols)
  const int sg   = cs >> 2;        // subgroup 0..7 (4 WGs each)

  // barrier lines (256B spacing): qc 0..511, qf 512..1023, gcnt 1024..5119
  unsigned* qc   = bar + mq * 64;
  unsigned* qf   = bar + 512 + mq * 64;
  unsigned* gcnt = bar + 1024 + (mq * 8 + sg) * 64;

  const int r0 = lane & 15;        // row within m-tile / col within n-tile
  const int ch = lane >> 4;        // 16B chunk id within K-slice

  // ---- Wh fragments in registers: volatile loads (non-remat), 128 regs ----
  bf16x8 bfr[32];
  {
    const unsigned short* bp = WhT + (size_t)(cs * 128 + nh * 16 + r0) * 1024 + ch * 8;
#pragma unroll
    for (int ks = 0; ks < 32; ++ks)
      bfr[ks] = *(const volatile bf16x8*)(bp + ks * 32);
  }

  // ---- per-thread cell ownership: ALL 512 threads, 1 cell each ----
  const int erow  = tid >> 5;            // 0..15 (row within group)
  const int ecol  = tid & 31;            // cell col within slice
  const int browg = mq * 16 + erow;      // global batch row
  float cf = 0.f;

  const unsigned short* xwp = XW + (size_t)browg * 256 * 4096 + cs * 128 + ecol * 4;
  // u32 store pointers (even lanes store cols {ecol, ecol+1})
  unsigned* c0p = (unsigned*)(cB0 + (size_t)browg * 1024 + cs * 32 + ecol);
  unsigned* c1p = (unsigned*)(cB1 + (size_t)browg * 1024 + cs * 32 + ecol);
  unsigned* hp  = (unsigned*)(H + (size_t)browg * 256 * 1024 + cs * 32 + ecol);

  // staging geometry: thread covers rows {4it+strow}, 16B chunk stcc
  const int strow = tid >> 7;            // 0..3
  const int stcc  = tid & 127;           // 0..127

  // prologue: xw for t=0
  u16x4 xw = *(const u16x4*)(xwp);

  for (int t = 0; t < 256; ++t) {
    const unsigned short* cinq = ((t & 1) ? cB1 : cB0) + (size_t)mq * 16 * 1024;

    // ---- stage A-tile [16][1024] bf16: coherent loads -> regs -> LDS ----
    u32x4 st[4];
#pragma unroll
    for (int it = 0; it < 4; ++it) {
      const void* p = cinq + (size_t)(it * 4 + strow) * 1024 + stcc * 8;
      asm volatile("global_load_dwordx4 %0, %1, off sc0 sc1"
                   : "=&v"(st[it]) : "v"(p) : "memory");
    }
    asm volatile("s_waitcnt vmcnt(0)" ::: "memory");
    __builtin_amdgcn_sched_barrier(0);
#pragma unroll
    for (int it = 0; it < 4; ++it) {
      int r = it * 4 + strow;
      *(u32x4*)&sA[r * 2064 + stcc * 16] = st[it];
    }
    __syncthreads();   // sA ready

    // ---- GEMM: one 16x16 tile per wave, K=1024; A LDS, B regs ----
    f32x4 acc = (f32x4){0.f, 0.f, 0.f, 0.f};
#pragma unroll
    for (int ks = 0; ks < 32; ++ks) {
      bf16x8 a0 = *(const bf16x8*)&sA[r0 * 2064 + (ch + ks * 4) * 16];
      acc = MFMA(a0, bfr[ks], acc);
    }

    // ---- redistribute preacts via LDS ----
#pragma unroll
    for (int rr = 0; rr < 4; ++rr)
      sP[(ch * 4 + rr) * 132 + nh * 16 + r0] = acc[rr];
    __syncthreads();   // sP ready

    // ---- critical-path elementwise: c2 only (3 transcendentals) ----
    float4 g = *(const float4*)&sP[erow * 132 + ecol * 4];
    float pf = g.x + b2f((unsigned short)xw[0]);
    float pi = g.y + b2f((unsigned short)xw[1]);
    float pg = g.z + b2f((unsigned short)xw[2]);
    float f  = sigmoidf_(pf), i1 = sigmoidf_(pi), gg = tanhf_(pg);
    float c2 = cf * f + i1 * gg; cf = c2;

    // cell: pack adjacent cols via shfl, even lanes agent-store u32 to MALL
    unsigned cl = f2b(c2);
    unsigned chi = __shfl_down(cl, 1);
    if (!(lane & 1))
      __hip_atomic_store((t & 1) ? c0p : c1p, cl | (chi << 16),
                         __ATOMIC_RELAXED, __HIP_MEMORY_SCOPE_AGENT);

    // ---- drain: all cell stores at MALL, then signal ----
    __syncthreads();
    if (tid == 0) {
      unsigned tgt1 = 4u * (unsigned)(t + 1);
      unsigned tgt2 = 8u * (unsigned)(t + 1);
      unsigned n = __hip_atomic_fetch_add(gcnt, 1u, __ATOMIC_RELAXED,
                                          __HIP_MEMORY_SCOPE_AGENT);
      if (n == tgt1 - 1u) {
        unsigned m = __hip_atomic_fetch_add(qc, 1u, __ATOMIC_RELAXED,
                                            __HIP_MEMORY_SCOPE_AGENT);
        if (m == tgt2 - 1u)
          __hip_atomic_store(qf, (unsigned)(t + 1),
                             __ATOMIC_RELAXED, __HIP_MEMORY_SCOPE_AGENT);
      }
    }

    // ---- spin-window work: h + H store (not needed by consumers) ----
    {
      float po = g.w + b2f((unsigned short)xw[3]);
      float h  = sigmoidf_(po) * tanhf_(c2);
      unsigned hl = f2b(h);
      unsigned hh = __shfl_down(hl, 1);
      if (!(lane & 1))
        *(hp + (size_t)t * 512) = hl | (hh << 16);   // u32 ptr: row stride 1024 elem = 512 u32
    }
    // prefetch next step's XW row (read-only stream)
    if (t < 255) xw = *(const u16x4*)(xwp + (size_t)(t + 1) * 4096);

    if (tid == 0) {
      while (__hip_atomic_load(qf, __ATOMIC_RELAXED, __HIP_MEMORY_SCOPE_AGENT)
             < (unsigned)(t + 1))
        __builtin_amdgcn_s_sleep(1);
    }
    __syncthreads();   // release
  }

  // final f32 cell state from registers (kernel-end flush covers it)
  cellOut[(size_t)browg * 1024 + cs * 32 + ecol] = cf;
}

// ---------- launcher ----------
extern "C" void kernel_launch(void* const* d_in, const int* in_sizes, int n_in,
                              void* d_out, int out_size, void* d_ws, size_t ws_size,
                              hipStream_t stream) {
  const float* x   = (const float*)d_in[0];
  const float* Wf  = (const float*)d_in[1];
  const float* bfv = (const float*)d_in[2];
  const float* Wi1 = (const float*)d_in[3];
  const float* bi1 = (const float*)d_in[4];
  const float* Wi2 = (const float*)d_in[5];
  const float* bi2 = (const float*)d_in[6];
  const float* Wo  = (const float*)d_in[7];
  const float* bo  = (const float*)d_in[8];
  const float* Wc  = (const float*)d_in[9];
  const float* bc  = (const float*)d_in[10];
  float* out = (float*)d_out;

  if (ws_size < WS_NEEDED) return;  // visible failure instead of corruption

  char* ws = (char*)d_ws;
  unsigned short* xb      = (unsigned short*)(ws + OFF_XB);
  unsigned short* WhT     = (unsigned short*)(ws + OFF_WHT);
  unsigned short* WxT     = (unsigned short*)(ws + OFF_WXT);
  unsigned short* WcT     = (unsigned short*)(ws + OFF_WCT);
  float*          biasAll = (float*)(ws + OFF_BIAS);
  unsigned short* XW      = (unsigned short*)(ws + OFF_XW);
  unsigned short* H       = (unsigned short*)(ws + OFF_H);
  unsigned short* cB0     = (unsigned short*)(ws + OFF_CB);
  unsigned short* cB1     = (unsigned short*)(ws + OFF_CB + (size_t)128 * 1024 * 2);
  unsigned*       barLn   = (unsigned*)(ws + OFF_BAR);
  float*          cellOut = out + (size_t)32768 * 1024;

  hipMemsetAsync(cB0, 0, (size_t)128 * 1024 * 2, stream);
  hipMemsetAsync(barLn, 0, 32768, stream);    // reset barrier lines EVERY launch

  cvt_x_kernel <<<32768, 256, 0, stream>>>(x, xb);
  cvt_w_kernel <<< 1024, 256, 0, stream>>>(Wf, Wi1, Wi2, Wo, WhT, WxT);
  bias_kernel  <<<   16, 256, 0, stream>>>(bfv, bi1, bi2, bo, biasAll);
  cvt_wc_kernel<<< 4096, 256, 0, stream>>>(Wc, WcT);

  // XW = x @ Wx_all + biases   (M=32768, N=4096, K=1024), bf16 out, 256^2 tiles
  gemm_bt<false><<<dim3(16, 128), 512, 0, stream>>>(xb, WxT, biasAll, XW, 32768, 4096, 1024);

  // persistent recurrence: 256 WGs x 512 threads (proven envelope), cooperative
  {
    void* args[] = { (void*)&WhT, (void*)&XW, (void*)&H,
                     (void*)&cB0, (void*)&cB1, (void*)&cellOut, (void*)&barLn };
    hipLaunchCooperativeKernel(lstm_persist, dim3(256), dim3(512), args, 0u, stream);
  }

  // output_sequence = h @ Wc + bc  (M=32768, N=1024, K=1024), f32 out
  gemm_bt<true><<<dim3(4, 128), 512, 0, stream>>>(H, WcT, bc, out, 32768, 1024, 1024);
}